// Round 17
// baseline (230.789 us; speedup 1.0000x reference)
//
#include <hip/hip_runtime.h>
#include <hip/hip_bf16.h>

typedef __hip_bfloat16 bf16;
typedef __attribute__((ext_vector_type(4))) float f32x4;
typedef __attribute__((ext_vector_type(8))) short bf16x8;
typedef __attribute__((ext_vector_type(4))) short s16x4;

#define BB 16
#define HH 128
#define WW 128
#define HWSZ (HH*WW)
// xT: [16][136][136][64] bf16, pad 4
#define XH 136
#define XW 136
#define XPAD 4
// catT: [16][130][130][192] bf16, pad 1
#define CHH 130
#define CWD 130
#define CPAD 1
#define CATC 192

// ---------------- zero pad borders + pooled accumulators (one launch) ----------------
__device__ __forceinline__ void zero_border_body(bf16* __restrict__ base, int HP, int WP,
                                                 int PAD, int Cdim, int slots)
{
    int cg8 = Cdim >> 3;
    int per_b = slots * cg8;
    int idx = blockIdx.x * 256 + threadIdx.x;
    if (idx >= BB * per_b) return;
    int b = idx / per_b;
    int rem = idx - b * per_b;
    int slot = rem / cg8;
    int cg = rem - slot * cg8;
    int top = PAD * WP;
    int h, w;
    if (slot < top)            { h = slot / WP;            w = slot % WP; }
    else if (slot < 2 * top)   { int s = slot - top;       h = HP - PAD + s / WP; w = s % WP; }
    else {
        int s = slot - 2 * top;
        int row = s / (2 * PAD), t = s - row * (2 * PAD);
        h = PAD + row;
        w = (t < PAD) ? t : (WP - 2 * PAD + t);
    }
    bf16x8 z = {0,0,0,0,0,0,0,0};
    *(bf16x8*)(base + (((size_t)b * HP + h) * WP + w) * Cdim + cg * 8) = z;
}

__global__ void init_borders(bf16* __restrict__ xT, bf16* __restrict__ catT,
                             float* __restrict__ pooledx, float* __restrict__ pooledc)
{
    if (blockIdx.y == 0) {
        if (blockIdx.x == 0) {      // also zero pooled accumulators
            for (int i = threadIdx.x; i < BB * 64;   i += 256) pooledx[i] = 0.f;
            for (int i = threadIdx.x; i < BB * CATC; i += 256) pooledc[i] = 0.f;
        }
        zero_border_body(xT,   XH,  XW,  XPAD, 64,   2112);
    } else {
        zero_border_body(catT, CHH, CWD, CPAD, CATC, 516);
    }
}

// ---------------- LDS-tiled transpose + pad x -> bf16 channel-fast, fused pool ----------------
__global__ __launch_bounds__(256)
void transpose_pad_pool_x(const float* __restrict__ x, bf16* __restrict__ xT,
                          float* __restrict__ pooledx)
{
    __shared__ float tile[128 * 65];
    const int h = blockIdx.x, b = blockIdx.y;
    const int t = threadIdx.x;
    const int w  = t & 127;
    const int chalf = t >> 7;            // 0/1

    const float* xb = x + (((size_t)b * 64) * HH + h) * WW + w;
    #pragma unroll
    for (int it = 0; it < 32; ++it) {
        int c = it * 2 + chalf;
        tile[w * 65 + c] = xb[(size_t)c * HWSZ];
    }
    __syncthreads();

    bf16* dst = xT + (((size_t)b * XH + (h + XPAD)) * XW + XPAD) * 64;
    #pragma unroll
    for (int it = 0; it < 4; ++it) {
        int v  = t + it * 256;           // 0..1023
        int ww = v >> 3;
        int c0 = (v & 7) * 8;
        const float* src = tile + ww * 65 + c0;
        bf16x8 pk;
        #pragma unroll
        for (int j = 0; j < 8; ++j)
            pk[j] = __builtin_bit_cast(short, __float2bfloat16(src[j]));
        *(bf16x8*)(dst + (size_t)ww * 64 + c0) = pk;
    }

    if (t < 64) {
        float s = 0.f;
        #pragma unroll 4
        for (int ww = 0; ww < 128; ++ww) s += tile[ww * 65 + t];
        atomicAdd(pooledx + b * 64 + t, s);
    }
}

// ---------------- attention MLP body ----------------
__device__ __forceinline__ void attn_body(int b, const float* pooled, int Cin,
                                          const float* fc1, int hid,
                                          const float* fc2w, const float* fc2b,
                                          float* att, float* sp, float* sh, float* slg)
{
    for (int c = threadIdx.x; c < Cin; c += 64) sp[c] = pooled[b * Cin + c];
    __syncthreads();
    int j = threadIdx.x;
    if (j < hid) {
        float s = 0.f;
        const float4* f4 = (const float4*)(fc1 + (size_t)j * Cin);
        for (int c4 = 0; c4 < Cin / 4; ++c4) {
            float4 v = f4[c4];
            s += v.x * sp[c4*4+0] + v.y * sp[c4*4+1] + v.z * sp[c4*4+2] + v.w * sp[c4*4+3];
        }
        sh[j] = s > 0.f ? s * (1.0f / 16384.0f) : 0.f;   // fold 1/HW
    }
    __syncthreads();
    int k = threadIdx.x;
    if (k < 4) {
        float s = fc2b[k];
        for (int jj = 0; jj < hid; ++jj) s += fc2w[k * hid + jj] * sh[jj];
        slg[k] = s * (1.0f / 34.0f);
    }
    __syncthreads();
    if (threadIdx.x == 0) {
        float m = fmaxf(fmaxf(slg[0], slg[1]), fmaxf(slg[2], slg[3]));
        float e0 = expf(slg[0]-m), e1 = expf(slg[1]-m), e2 = expf(slg[2]-m), e3 = expf(slg[3]-m);
        float inv = 1.0f / (e0+e1+e2+e3);
        att[b*4+0] = e0*inv; att[b*4+1] = e1*inv; att[b*4+2] = e2*inv; att[b*4+3] = e3*inv;
    }
}

__global__ void attention3(const float* __restrict__ pooled,
                           const float* f1a, const float* f2a, const float* ba, float* aa,
                           const float* f1b, const float* f2b, const float* bb, float* ab,
                           const float* f1c, const float* f2c, const float* bc, float* ac)
{
    __shared__ float sp[192], sh[64], slg[4];
    int br = blockIdx.y;
    const float* fc1  = br == 0 ? f1a : br == 1 ? f1b : f1c;
    const float* fc2w = br == 0 ? f2a : br == 1 ? f2b : f2c;
    const float* fc2b = br == 0 ? ba  : br == 1 ? bb  : bc;
    float* att        = br == 0 ? aa  : br == 1 ? ab  : ac;
    attn_body(blockIdx.x, pooled, 64, fc1, 17, fc2w, fc2b, att, sp, sh, slg);
}

__global__ void attention_one(const float* __restrict__ pooled, int Cin,
                              const float* __restrict__ fc1, int hid,
                              const float* __restrict__ fc2w,
                              const float* __restrict__ fc2b, float* __restrict__ att)
{
    __shared__ float sp[192], sh[64], slg[4];
    attn_body(blockIdx.x, pooled, Cin, fc1, hid, fc2w, fc2b, att, sp, sh, slg);
}

// ---------------- aggregate weights -> bf16, MFMA A-fragment order ----------------
// Slot layout: [b][s = chunk*9+tap][m 4][lane 64][j 8] bf16.
// PERM=false: slot (m,l15) holds logical channel co = m*16 + l15 (final conv).
// PERM=true:  slot (m,l15) holds logical channel co = l15*4 + m (branches).
template<int CIN, bool PERM>
__device__ __forceinline__ void aggw_body(const float* __restrict__ w,
                                          const float* __restrict__ att,
                                          bf16* __restrict__ out, float* wl)
{
    constexpr int C9 = CIN * 9;
    constexpr int NS = (CIN / 32) * 9;
    const int co = blockIdx.x, b = blockIdx.y;
    const int src = PERM ? ((co & 15) * 4 + (co >> 4)) : co;
    for (int i = threadIdx.x; i < 4 * C9; i += 256) {
        int k = i / C9, rem = i - k * C9;
        wl[i] = w[((size_t)k * 64 + src) * C9 + rem];
    }
    __syncthreads();
    float a0 = att[b*4+0], a1 = att[b*4+1], a2 = att[b*4+2], a3 = att[b*4+3];
    const int m = co >> 4, l15 = co & 15;
    char* ob = (char*)out + (size_t)b * NS * 4096;
    for (int t = threadIdx.x; t < NS * 32; t += 256) {
        int s = t >> 5, rem = t & 31;
        int gg = rem >> 3, j = rem & 7;
        int chunk = s / 9, tap = s - chunk * 9;
        int ci = chunk * 32 + gg * 8 + j;
        float v = a0 * wl[ci*9 + tap] + a1 * wl[C9 + ci*9 + tap]
                + a2 * wl[2*C9 + ci*9 + tap] + a3 * wl[3*C9 + ci*9 + tap];
        *(bf16*)(ob + ((size_t)((s*4 + m) * 64 + (gg*16 + l15))) * 16 + j * 2) = __float2bfloat16(v);
    }
}

// fused: 3 branch weight aggregations, grid (64, 16, 3)
__global__ void aggw_frag3(const float* __restrict__ w1, const float* __restrict__ att1, bf16* o1,
                           const float* __restrict__ w2, const float* __restrict__ att2, bf16* o2,
                           const float* __restrict__ w3, const float* __restrict__ att3, bf16* o3)
{
    __shared__ float wl[4 * 64 * 9];
    int z = blockIdx.z;
    if (z == 0)      aggw_body<64, true>(w1, att1, o1, wl);
    else if (z == 1) aggw_body<64, true>(w2, att2, o2, wl);
    else             aggw_body<64, true>(w3, att3, o3, wl);
}

__global__ void aggw_frag_t(const float* __restrict__ w, const float* __restrict__ att,
                            bf16* __restrict__ out)
{
    __shared__ float wl[4 * 192 * 9];
    aggw_body<192, false>(w, att, out, wl);
}

// ---------------- MFMA implicit-GEMM conv core (branch convs, 8-wave) ----------------
template<int DIL, int CIN>
__device__ __forceinline__ void conv_core(
    int b, int hb, int wt,
    const bf16* __restrict__ inT, int HPd, int WPd, int PAD,
    const bf16* __restrict__ aggwF,
    bf16* __restrict__ catT, int catbase, float* __restrict__ poolc,
    char* lds, float* sco)
{
    constexpr int NCHUNK = CIN / 32;
    constexpr int SLOTS  = 64 + 2 * DIL;
    constexpr int ROWB   = SLOTS * 64;
    constexpr int XBYTES = 10 * ROWB;
    constexpr int XSEG   = (XBYTES + 1023) / 1024;
    constexpr int ABYTES = 36864;
    constexpr int MAXT   = (XSEG + 7) / 8;

    const int r  = hb % DIL;
    const int q  = hb / DIL;
    const int tid  = threadIdx.x;
    const int wv   = tid >> 6;
    const int lane = tid & 63;
    const int n16  = lane & 15;
    const int g    = lane >> 4;

    const char* inB = (const char*)inT;
    const char* awB = (const char*)aggwF + (size_t)b * (NCHUNK * ABYTES);

    if (tid < 64) sco[tid] = 0.f;

    int baddr[12];
    #pragma unroll
    for (int nt = 0; nt < 4; ++nt)
        #pragma unroll
        for (int kw = 0; kw < 3; ++kw)
            baddr[nt*3+kw] = wv * ROWB + g * (SLOTS * 16)
                             + (nt * 16 + n16 + kw * DIL) * 16;

    int xoff[MAXT];
    #pragma unroll
    for (int t = 0; t < MAXT; ++t) {
        int i = wv + 8 * t;
        xoff[t] = 0;
        if (i < XSEG) {
            int o = i * 1024 + lane * 16;
            if (o < XBYTES) {
                int row  = o / ROWB;
                int rem  = o - row * ROWB;
                int g2   = rem / (SLOTS * 16);
                int slot = (rem - g2 * (SLOTS * 16)) >> 4;
                int h_in = (q * 8 + row - 1) * DIL + r;
                xoff[t] = ((b * HPd + PAD + h_in) * WPd + (PAD + wt * 64 - DIL + slot)) * (CIN * 2)
                          + g2 * 16;
            }
        }
    }

    auto stage = [&](int c) {
        #pragma unroll
        for (int t = 0; t < MAXT; ++t) {
            int i = wv + 8 * t;
            if (i >= XSEG) break;
            __builtin_amdgcn_global_load_lds(
                (const __attribute__((address_space(1))) void*)(inB + (size_t)(xoff[t] + c * 64)),
                (__attribute__((address_space(3))) void*)(lds + i * 1024), 16, 0, 0);
        }
    };

    f32x4 acc[4][4];
    #pragma unroll
    for (int nt = 0; nt < 4; ++nt)
        #pragma unroll
        for (int m = 0; m < 4; ++m) { f32x4 z = {0.f,0.f,0.f,0.f}; acc[nt][m] = z; }

    for (int c = 0; c < NCHUNK; ++c) {
        stage(c);
        __syncthreads();
        const char* awC = awB + (size_t)c * ABYTES + (size_t)lane * 16;
        #pragma unroll 3
        for (int tap = 0; tap < 9; ++tap) {
            const int kh = tap / 3, kw = tap - kh * 3;
            bf16x8 a[4];
            #pragma unroll
            for (int m = 0; m < 4; ++m)
                a[m] = *(const bf16x8*)(awC + (size_t)((tap * 4 + m) * 1024));
            #pragma unroll
            for (int nt = 0; nt < 4; ++nt) {
                const bf16x8 bfr = *(const bf16x8*)(lds + baddr[nt * 3 + kw] + kh * ROWB);
                #pragma unroll
                for (int m = 0; m < 4; ++m)
                    acc[nt][m] = __builtin_amdgcn_mfma_f32_16x16x32_bf16(a[m], bfr, acc[nt][m], 0, 0, 0);
            }
        }
        __syncthreads();
    }

    // ---- epilogue: leaky -> catT (coalesced, PERM'd) + pooled sums ----
    const int h_out = (q * 8 + wv) * DIL + r;
    float csum[4][4];
    #pragma unroll
    for (int m = 0; m < 4; ++m)
        #pragma unroll
        for (int qq = 0; qq < 4; ++qq) csum[m][qq] = 0.f;
    #pragma unroll
    for (int nt = 0; nt < 4; ++nt) {
        int w_out = wt * 64 + nt * 16 + n16;
        char* dst = (char*)(catT + (((size_t)b * CHH + (CPAD + h_out)) * CWD + (CPAD + w_out)) * CATC
                            + catbase) + g * 32;
        float lv[4][4];
        #pragma unroll
        for (int m = 0; m < 4; ++m)
            #pragma unroll
            for (int qq = 0; qq < 4; ++qq) {
                float v = acc[nt][m][qq];
                v = v >= 0.f ? v : 0.1f * v;        // leaky
                lv[m][qq] = v;
                csum[m][qq] += v;
            }
        bf16x8 lo, hi;
        #pragma unroll
        for (int j = 0; j < 8; ++j) {
            lo[j] = __builtin_bit_cast(short, __float2bfloat16(lv[j & 3][j >> 2]));
            hi[j] = __builtin_bit_cast(short, __float2bfloat16(lv[j & 3][2 + (j >> 2)]));
        }
        *(bf16x8*)(dst)      = lo;                  // ch [16g, 16g+8)
        *(bf16x8*)(dst + 16) = hi;                  // ch [16g+8, 16g+16)
    }
    #pragma unroll
    for (int m = 0; m < 4; ++m)
        #pragma unroll
        for (int qq = 0; qq < 4; ++qq) {
            float v = csum[m][qq];
            v += __shfl_xor(v, 1, 64);
            v += __shfl_xor(v, 2, 64);
            v += __shfl_xor(v, 4, 64);
            v += __shfl_xor(v, 8, 64);
            if (n16 == 0) atomicAdd(&sco[g * 16 + qq * 4 + m], v);
        }
    __syncthreads();
    if (tid < 64) atomicAdd(poolc + b * CATC + catbase + tid, sco[tid]);
}

// merged 3-branch dispatch: 1536 blocks 1D, XCD-banded mapping.
__global__ __launch_bounds__(512, 4)
void conv_branch3(const bf16* __restrict__ xT,
                  const bf16* __restrict__ aggF1, const bf16* __restrict__ aggF2,
                  const bf16* __restrict__ aggF3,
                  bf16* __restrict__ catT, float* __restrict__ poolc)
{
    constexpr int SCOO = 46080;                  // max X region (DIL4: 45 segs)
    __shared__ __align__(1024) char lds[SCOO + 256];
    float* sco = (float*)(lds + SCOO);

    const int bid  = blockIdx.x;
    const int xcd  = bid & 7;
    const int j    = bid >> 3;                   // 0..191
    const int b    = 2 * xcd + (j >= 96 ? 1 : 0);
    const int u    = j % 96;
    const int band = u / 24;                     // 0..3 (32-row band)
    const int v    = u % 24;
    const int br   = v % 3;
    const int t2   = v / 3;                      // 0..7
    const int wt   = t2 & 1;
    const int hb   = band * 4 + (t2 >> 1);       // hb in {4band..4band+3} for ALL dilations

    if (br == 0)
        conv_core<1, 64>(b, hb, wt, xT, XH, XW, XPAD, aggF1, catT, 0,   poolc, lds, sco);
    else if (br == 1)
        conv_core<2, 64>(b, hb, wt, xT, XH, XW, XPAD, aggF2, catT, 64,  poolc, lds, sco);
    else
        conv_core<4, 64>(b, hb, wt, xT, XH, XW, XPAD, aggF3, catT, 128, poolc, lds, sco);
}

// ---------------- final conv + residual: 4-wave blocks, 4 barrier domains/CU ----------------
// 256 threads = 4 waves; block = 64 co x 4 rows x 64 w; wave = 1 row.
// X: single buffer, 6 rows x 66 slots g-major = 25.3 KB -> up to 4 blocks/CU
// (16 waves/CU in 4 independent barrier domains vs 2 with 8-wave blocks).
#define FF_ROWB 4224                 // 66 slots * 64 B
#define FF_XBY  25344                // 6 rows
#define FF_XSEG 25

__global__ __launch_bounds__(256, 4)
void conv_final(const bf16* __restrict__ catT, const bf16* __restrict__ aggFt,
                const float* __restrict__ x, float* __restrict__ out)
{
    __shared__ __align__(1024) char lds[FF_XSEG * 1024];

    const int bid = blockIdx.x;                  // 1024 blocks, XCD-banded
    const int xcd = bid & 7;
    const int j   = bid >> 3;                    // 0..127
    const int b   = 2 * xcd + (j >= 64 ? 1 : 0);
    const int u   = j & 63;
    const int wt  = u & 1;
    const int hb  = u >> 1;                      // 0..31 (4-row groups)

    const int tid  = threadIdx.x;
    const int wv   = tid >> 6;                   // 0..3
    const int lane = tid & 63;
    const int n16  = lane & 15;
    const int g    = lane >> 4;

    const char* inB = (const char*)catT;
    const char* awB = (const char*)aggFt + (size_t)b * (6 * 36864);

    int baddr[12];
    #pragma unroll
    for (int nt = 0; nt < 4; ++nt)
        #pragma unroll
        for (int kw = 0; kw < 3; ++kw)
            baddr[nt*3+kw] = wv * FF_ROWB + g * (66 * 16) + (nt * 16 + n16 + kw) * 16;

    int xoff[7];
    #pragma unroll
    for (int t = 0; t < 7; ++t) {
        int i = wv + 4 * t;
        xoff[t] = 0;
        if (i < FF_XSEG) {
            int o = i * 1024 + lane * 16;
            if (o < FF_XBY) {
                int row  = o / FF_ROWB;
                int rem  = o - row * FF_ROWB;
                int g2   = rem / (66 * 16);
                int slot = (rem - g2 * (66 * 16)) >> 4;
                int h_in = hb * 4 + row - 1;
                xoff[t] = ((b * CHH + CPAD + h_in) * CWD + (CPAD + wt * 64 - 1 + slot)) * (CATC * 2)
                          + g2 * 16;
            }
        }
    }

    auto stage = [&](int c) {
        #pragma unroll
        for (int t = 0; t < 7; ++t) {
            int i = wv + 4 * t;
            if (i >= FF_XSEG) break;
            __builtin_amdgcn_global_load_lds(
                (const __attribute__((address_space(1))) void*)(inB + (size_t)(xoff[t] + c * 64)),
                (__attribute__((address_space(3))) void*)(lds + i * 1024), 16, 0, 0);
        }
    };

    f32x4 acc[4][4];
    #pragma unroll
    for (int nt = 0; nt < 4; ++nt)
        #pragma unroll
        for (int m = 0; m < 4; ++m) { f32x4 z = {0.f,0.f,0.f,0.f}; acc[nt][m] = z; }

    for (int c = 0; c < 6; ++c) {
        stage(c);
        __syncthreads();
        const char* awC = awB + (size_t)c * 36864 + (size_t)lane * 16;
        #pragma unroll 3
        for (int tap = 0; tap < 9; ++tap) {
            const int kh = tap / 3, kw = tap - kh * 3;
            bf16x8 a[4];
            #pragma unroll
            for (int m = 0; m < 4; ++m)
                a[m] = *(const bf16x8*)(awC + (size_t)((tap * 4 + m) * 1024));
            #pragma unroll
            for (int nt = 0; nt < 4; ++nt) {
                const bf16x8 bfr = *(const bf16x8*)(lds + baddr[nt * 3 + kw] + kh * FF_ROWB);
                #pragma unroll
                for (int m = 0; m < 4; ++m)
                    acc[nt][m] = __builtin_amdgcn_mfma_f32_16x16x32_bf16(a[m], bfr, acc[nt][m], 0, 0, 0);
            }
        }
        __syncthreads();
    }

    const int h_out = hb * 4 + wv;
    #pragma unroll
    for (int nt = 0; nt < 4; ++nt) {
        int w_out = wt * 64 + nt * 16 + n16;
        #pragma unroll
        for (int m = 0; m < 4; ++m) {
            int co = m * 16 + g * 4;
            size_t base = (((size_t)b * 64 + co) * HH + h_out) * WW + w_out;
            #pragma unroll
            for (int qq = 0; qq < 4; ++qq) {
                size_t idx = base + (size_t)qq * HWSZ;
                out[idx] = x[idx] + acc[nt][m][qq];
            }
        }
    }
}

// ---------------- launch ----------------
extern "C" void kernel_launch(void* const* d_in, const int* in_sizes, int n_in,
                              void* d_out, int out_size, void* d_ws, size_t ws_size,
                              hipStream_t stream) {
    const float* x      = (const float*)d_in[0];
    const float* w1     = (const float*)d_in[1];
    const float* fc1_1  = (const float*)d_in[2];
    const float* fc2w_1 = (const float*)d_in[3];
    const float* fc2b_1 = (const float*)d_in[4];
    const float* w2     = (const float*)d_in[5];
    const float* fc1_2  = (const float*)d_in[6];
    const float* fc2w_2 = (const float*)d_in[7];
    const float* fc2b_2 = (const float*)d_in[8];
    const float* w3     = (const float*)d_in[9];
    const float* fc1_3  = (const float*)d_in[10];
    const float* fc2w_3 = (const float*)d_in[11];
    const float* fc2b_3 = (const float*)d_in[12];
    const float* wt     = (const float*)d_in[13];
    const float* fc1_t  = (const float*)d_in[14];
    const float* fc2w_t = (const float*)d_in[15];
    const float* fc2b_t = (const float*)d_in[16];
    float* out = (float*)d_out;
    (void)in_sizes; (void)n_in; (void)out_size; (void)ws_size;

    char* ws = (char*)d_ws;
    auto alloc = [&](size_t bytes) { char* p = ws; ws += (bytes + 255) & ~(size_t)255; return p; };

    bf16*  aggF1   = (bf16*)alloc((size_t)BB * 18 * 4096);
    bf16*  aggF2   = (bf16*)alloc((size_t)BB * 18 * 4096);
    bf16*  aggF3   = (bf16*)alloc((size_t)BB * 18 * 4096);
    bf16*  aggFt   = (bf16*)alloc((size_t)BB * 54 * 4096);
    float* pooledx = (float*)alloc(BB * 64 * 4);
    float* pooledc = (float*)alloc(BB * 192 * 4);
    float* att1    = (float*)alloc(BB * 4 * 4);
    float* att2    = (float*)alloc(BB * 4 * 4);
    float* att3    = (float*)alloc(BB * 4 * 4);
    float* attt    = (float*)alloc(BB * 4 * 4);
    alloc(65536);                                            // guard
    const size_t XT_BYTES  = (size_t)BB * XH * XW * 64 * 2;
    bf16* xT   = (bf16*)alloc(XT_BYTES);
    alloc(65536);                                            // guard
    const size_t CAT_BYTES = (size_t)BB * CHH * CWD * CATC * 2;
    bf16* catT = (bf16*)alloc(CAT_BYTES);
    alloc(65536);                                            // guard

    // border + pooled zeroing, one launch
    init_borders<<<dim3(1056, 2), 256, 0, stream>>>(xT, catT, pooledx, pooledc);

    transpose_pad_pool_x<<<dim3(128, 16), 256, 0, stream>>>(x, xT, pooledx);

    attention3<<<dim3(16, 3), 64, 0, stream>>>(pooledx,
        fc1_1, fc2w_1, fc2b_1, att1,
        fc1_2, fc2w_2, fc2b_2, att2,
        fc1_3, fc2w_3, fc2b_3, att3);

    aggw_frag3<<<dim3(64, 16, 3), 256, 0, stream>>>(w1, att1, aggF1,
                                                    w2, att2, aggF2,
                                                    w3, att3, aggF3);

    conv_branch3<<<1536, 512, 0, stream>>>(xT, aggF1, aggF2, aggF3, catT, pooledc);

    attention_one<<<16, 64, 0, stream>>>(pooledc, CATC, fc1_t, 49, fc2w_t, fc2b_t, attt);
    aggw_frag_t<<<dim3(64, 16), 256, 0, stream>>>(wt, attt, aggFt);

    conv_final<<<1024, 256, 0, stream>>>(catT, aggFt, x, out);
}

// Round 18
// 219.322 us; speedup vs baseline: 1.0523x; 1.0523x over previous
//
#include <hip/hip_runtime.h>
#include <hip/hip_bf16.h>

typedef __hip_bfloat16 bf16;
typedef __attribute__((ext_vector_type(4))) float f32x4;
typedef __attribute__((ext_vector_type(8))) short bf16x8;
typedef __attribute__((ext_vector_type(4))) short s16x4;

#define BB 16
#define HH 128
#define WW 128
#define HWSZ (HH*WW)
// xT: [16][136][136][64] bf16, pad 4
#define XH 136
#define XW 136
#define XPAD 4
// catT: [16][130][130][192] bf16, pad 1
#define CHH 130
#define CWD 130
#define CPAD 1
#define CATC 192

// ---------------- zero pad borders + pooled accumulators (one launch) ----------------
__device__ __forceinline__ void zero_border_body(bf16* __restrict__ base, int HP, int WP,
                                                 int PAD, int Cdim, int slots)
{
    int cg8 = Cdim >> 3;
    int per_b = slots * cg8;
    int idx = blockIdx.x * 256 + threadIdx.x;
    if (idx >= BB * per_b) return;
    int b = idx / per_b;
    int rem = idx - b * per_b;
    int slot = rem / cg8;
    int cg = rem - slot * cg8;
    int top = PAD * WP;
    int h, w;
    if (slot < top)            { h = slot / WP;            w = slot % WP; }
    else if (slot < 2 * top)   { int s = slot - top;       h = HP - PAD + s / WP; w = s % WP; }
    else {
        int s = slot - 2 * top;
        int row = s / (2 * PAD), t = s - row * (2 * PAD);
        h = PAD + row;
        w = (t < PAD) ? t : (WP - 2 * PAD + t);
    }
    bf16x8 z = {0,0,0,0,0,0,0,0};
    *(bf16x8*)(base + (((size_t)b * HP + h) * WP + w) * Cdim + cg * 8) = z;
}

__global__ void init_borders(bf16* __restrict__ xT, bf16* __restrict__ catT,
                             float* __restrict__ pooledx, float* __restrict__ pooledc)
{
    if (blockIdx.y == 0) {
        if (blockIdx.x == 0) {      // also zero pooled accumulators
            for (int i = threadIdx.x; i < BB * 64;   i += 256) pooledx[i] = 0.f;
            for (int i = threadIdx.x; i < BB * CATC; i += 256) pooledc[i] = 0.f;
        }
        zero_border_body(xT,   XH,  XW,  XPAD, 64,   2112);
    } else {
        zero_border_body(catT, CHH, CWD, CPAD, CATC, 516);
    }
}

// ---------------- LDS-tiled transpose + pad x -> bf16 channel-fast, fused pool ----------------
__global__ __launch_bounds__(256)
void transpose_pad_pool_x(const float* __restrict__ x, bf16* __restrict__ xT,
                          float* __restrict__ pooledx)
{
    __shared__ float tile[128 * 65];
    const int h = blockIdx.x, b = blockIdx.y;
    const int t = threadIdx.x;
    const int w  = t & 127;
    const int chalf = t >> 7;            // 0/1

    const float* xb = x + (((size_t)b * 64) * HH + h) * WW + w;
    #pragma unroll
    for (int it = 0; it < 32; ++it) {
        int c = it * 2 + chalf;
        tile[w * 65 + c] = xb[(size_t)c * HWSZ];
    }
    __syncthreads();

    bf16* dst = xT + (((size_t)b * XH + (h + XPAD)) * XW + XPAD) * 64;
    #pragma unroll
    for (int it = 0; it < 4; ++it) {
        int v  = t + it * 256;           // 0..1023
        int ww = v >> 3;
        int c0 = (v & 7) * 8;
        const float* src = tile + ww * 65 + c0;
        bf16x8 pk;
        #pragma unroll
        for (int j = 0; j < 8; ++j)
            pk[j] = __builtin_bit_cast(short, __float2bfloat16(src[j]));
        *(bf16x8*)(dst + (size_t)ww * 64 + c0) = pk;
    }

    if (t < 64) {
        float s = 0.f;
        #pragma unroll 4
        for (int ww = 0; ww < 128; ++ww) s += tile[ww * 65 + t];
        atomicAdd(pooledx + b * 64 + t, s);
    }
}

// ---------------- attention MLP body ----------------
__device__ __forceinline__ void attn_body(int b, const float* pooled, int Cin,
                                          const float* fc1, int hid,
                                          const float* fc2w, const float* fc2b,
                                          float* att, float* sp, float* sh, float* slg)
{
    for (int c = threadIdx.x; c < Cin; c += 64) sp[c] = pooled[b * Cin + c];
    __syncthreads();
    int j = threadIdx.x;
    if (j < hid) {
        float s = 0.f;
        const float4* f4 = (const float4*)(fc1 + (size_t)j * Cin);
        for (int c4 = 0; c4 < Cin / 4; ++c4) {
            float4 v = f4[c4];
            s += v.x * sp[c4*4+0] + v.y * sp[c4*4+1] + v.z * sp[c4*4+2] + v.w * sp[c4*4+3];
        }
        sh[j] = s > 0.f ? s * (1.0f / 16384.0f) : 0.f;   // fold 1/HW
    }
    __syncthreads();
    int k = threadIdx.x;
    if (k < 4) {
        float s = fc2b[k];
        for (int jj = 0; jj < hid; ++jj) s += fc2w[k * hid + jj] * sh[jj];
        slg[k] = s * (1.0f / 34.0f);
    }
    __syncthreads();
    if (threadIdx.x == 0) {
        float m = fmaxf(fmaxf(slg[0], slg[1]), fmaxf(slg[2], slg[3]));
        float e0 = expf(slg[0]-m), e1 = expf(slg[1]-m), e2 = expf(slg[2]-m), e3 = expf(slg[3]-m);
        float inv = 1.0f / (e0+e1+e2+e3);
        att[b*4+0] = e0*inv; att[b*4+1] = e1*inv; att[b*4+2] = e2*inv; att[b*4+3] = e3*inv;
    }
}

__global__ void attention3(const float* __restrict__ pooled,
                           const float* f1a, const float* f2a, const float* ba, float* aa,
                           const float* f1b, const float* f2b, const float* bb, float* ab,
                           const float* f1c, const float* f2c, const float* bc, float* ac)
{
    __shared__ float sp[192], sh[64], slg[4];
    int br = blockIdx.y;
    const float* fc1  = br == 0 ? f1a : br == 1 ? f1b : f1c;
    const float* fc2w = br == 0 ? f2a : br == 1 ? f2b : f2c;
    const float* fc2b = br == 0 ? ba  : br == 1 ? bb  : bc;
    float* att        = br == 0 ? aa  : br == 1 ? ab  : ac;
    attn_body(blockIdx.x, pooled, 64, fc1, 17, fc2w, fc2b, att, sp, sh, slg);
}

__global__ void attention_one(const float* __restrict__ pooled, int Cin,
                              const float* __restrict__ fc1, int hid,
                              const float* __restrict__ fc2w,
                              const float* __restrict__ fc2b, float* __restrict__ att)
{
    __shared__ float sp[192], sh[64], slg[4];
    attn_body(blockIdx.x, pooled, Cin, fc1, hid, fc2w, fc2b, att, sp, sh, slg);
}

// ---------------- aggregate weights -> bf16, MFMA A-fragment order ----------------
// Slot layout: [b][s = chunk*9+tap][m 4][lane 64][j 8] bf16.
// PERM=false: slot (m,l15) holds logical channel co = m*16 + l15 (final conv).
// PERM=true:  slot (m,l15) holds logical channel co = l15*4 + m (branches).
template<int CIN, bool PERM>
__device__ __forceinline__ void aggw_body(const float* __restrict__ w,
                                          const float* __restrict__ att,
                                          bf16* __restrict__ out, float* wl)
{
    constexpr int C9 = CIN * 9;
    constexpr int NS = (CIN / 32) * 9;
    const int co = blockIdx.x, b = blockIdx.y;
    const int src = PERM ? ((co & 15) * 4 + (co >> 4)) : co;
    for (int i = threadIdx.x; i < 4 * C9; i += 256) {
        int k = i / C9, rem = i - k * C9;
        wl[i] = w[((size_t)k * 64 + src) * C9 + rem];
    }
    __syncthreads();
    float a0 = att[b*4+0], a1 = att[b*4+1], a2 = att[b*4+2], a3 = att[b*4+3];
    const int m = co >> 4, l15 = co & 15;
    char* ob = (char*)out + (size_t)b * NS * 4096;
    for (int t = threadIdx.x; t < NS * 32; t += 256) {
        int s = t >> 5, rem = t & 31;
        int gg = rem >> 3, j = rem & 7;
        int chunk = s / 9, tap = s - chunk * 9;
        int ci = chunk * 32 + gg * 8 + j;
        float v = a0 * wl[ci*9 + tap] + a1 * wl[C9 + ci*9 + tap]
                + a2 * wl[2*C9 + ci*9 + tap] + a3 * wl[3*C9 + ci*9 + tap];
        *(bf16*)(ob + ((size_t)((s*4 + m) * 64 + (gg*16 + l15))) * 16 + j * 2) = __float2bfloat16(v);
    }
}

// fused: 3 branch weight aggregations, grid (64, 16, 3)
__global__ void aggw_frag3(const float* __restrict__ w1, const float* __restrict__ att1, bf16* o1,
                           const float* __restrict__ w2, const float* __restrict__ att2, bf16* o2,
                           const float* __restrict__ w3, const float* __restrict__ att3, bf16* o3)
{
    __shared__ float wl[4 * 64 * 9];
    int z = blockIdx.z;
    if (z == 0)      aggw_body<64, true>(w1, att1, o1, wl);
    else if (z == 1) aggw_body<64, true>(w2, att2, o2, wl);
    else             aggw_body<64, true>(w3, att3, o3, wl);
}

__global__ void aggw_frag_t(const float* __restrict__ w, const float* __restrict__ att,
                            bf16* __restrict__ out)
{
    __shared__ float wl[4 * 192 * 9];
    aggw_body<192, false>(w, att, out, wl);
}

// ---------------- MFMA implicit-GEMM conv core (branch convs, 8-wave) ----------------
template<int DIL, int CIN>
__device__ __forceinline__ void conv_core(
    int b, int hb, int wt,
    const bf16* __restrict__ inT, int HPd, int WPd, int PAD,
    const bf16* __restrict__ aggwF,
    bf16* __restrict__ catT, int catbase, float* __restrict__ poolc,
    char* lds, float* sco)
{
    constexpr int NCHUNK = CIN / 32;
    constexpr int SLOTS  = 64 + 2 * DIL;
    constexpr int ROWB   = SLOTS * 64;
    constexpr int XBYTES = 10 * ROWB;
    constexpr int XSEG   = (XBYTES + 1023) / 1024;
    constexpr int ABYTES = 36864;
    constexpr int MAXT   = (XSEG + 7) / 8;

    const int r  = hb % DIL;
    const int q  = hb / DIL;
    const int tid  = threadIdx.x;
    const int wv   = tid >> 6;
    const int lane = tid & 63;
    const int n16  = lane & 15;
    const int g    = lane >> 4;

    const char* inB = (const char*)inT;
    const char* awB = (const char*)aggwF + (size_t)b * (NCHUNK * ABYTES);

    if (tid < 64) sco[tid] = 0.f;

    int baddr[12];
    #pragma unroll
    for (int nt = 0; nt < 4; ++nt)
        #pragma unroll
        for (int kw = 0; kw < 3; ++kw)
            baddr[nt*3+kw] = wv * ROWB + g * (SLOTS * 16)
                             + (nt * 16 + n16 + kw * DIL) * 16;

    int xoff[MAXT];
    #pragma unroll
    for (int t = 0; t < MAXT; ++t) {
        int i = wv + 8 * t;
        xoff[t] = 0;
        if (i < XSEG) {
            int o = i * 1024 + lane * 16;
            if (o < XBYTES) {
                int row  = o / ROWB;
                int rem  = o - row * ROWB;
                int g2   = rem / (SLOTS * 16);
                int slot = (rem - g2 * (SLOTS * 16)) >> 4;
                int h_in = (q * 8 + row - 1) * DIL + r;
                xoff[t] = ((b * HPd + PAD + h_in) * WPd + (PAD + wt * 64 - DIL + slot)) * (CIN * 2)
                          + g2 * 16;
            }
        }
    }

    auto stage = [&](int c) {
        #pragma unroll
        for (int t = 0; t < MAXT; ++t) {
            int i = wv + 8 * t;
            if (i >= XSEG) break;
            __builtin_amdgcn_global_load_lds(
                (const __attribute__((address_space(1))) void*)(inB + (size_t)(xoff[t] + c * 64)),
                (__attribute__((address_space(3))) void*)(lds + i * 1024), 16, 0, 0);
        }
    };

    f32x4 acc[4][4];
    #pragma unroll
    for (int nt = 0; nt < 4; ++nt)
        #pragma unroll
        for (int m = 0; m < 4; ++m) { f32x4 z = {0.f,0.f,0.f,0.f}; acc[nt][m] = z; }

    for (int c = 0; c < NCHUNK; ++c) {
        stage(c);
        __syncthreads();
        const char* awC = awB + (size_t)c * ABYTES + (size_t)lane * 16;
        #pragma unroll 3
        for (int tap = 0; tap < 9; ++tap) {
            const int kh = tap / 3, kw = tap - kh * 3;
            bf16x8 a[4];
            #pragma unroll
            for (int m = 0; m < 4; ++m)
                a[m] = *(const bf16x8*)(awC + (size_t)((tap * 4 + m) * 1024));
            #pragma unroll
            for (int nt = 0; nt < 4; ++nt) {
                const bf16x8 bfr = *(const bf16x8*)(lds + baddr[nt * 3 + kw] + kh * ROWB);
                #pragma unroll
                for (int m = 0; m < 4; ++m)
                    acc[nt][m] = __builtin_amdgcn_mfma_f32_16x16x32_bf16(a[m], bfr, acc[nt][m], 0, 0, 0);
            }
        }
        __syncthreads();
    }

    // ---- epilogue: leaky -> catT (coalesced, PERM'd) + pooled sums ----
    const int h_out = (q * 8 + wv) * DIL + r;
    float csum[4][4];
    #pragma unroll
    for (int m = 0; m < 4; ++m)
        #pragma unroll
        for (int qq = 0; qq < 4; ++qq) csum[m][qq] = 0.f;
    #pragma unroll
    for (int nt = 0; nt < 4; ++nt) {
        int w_out = wt * 64 + nt * 16 + n16;
        char* dst = (char*)(catT + (((size_t)b * CHH + (CPAD + h_out)) * CWD + (CPAD + w_out)) * CATC
                            + catbase) + g * 32;
        float lv[4][4];
        #pragma unroll
        for (int m = 0; m < 4; ++m)
            #pragma unroll
            for (int qq = 0; qq < 4; ++qq) {
                float v = acc[nt][m][qq];
                v = v >= 0.f ? v : 0.1f * v;        // leaky
                lv[m][qq] = v;
                csum[m][qq] += v;
            }
        bf16x8 lo, hi;
        #pragma unroll
        for (int j = 0; j < 8; ++j) {
            lo[j] = __builtin_bit_cast(short, __float2bfloat16(lv[j & 3][j >> 2]));
            hi[j] = __builtin_bit_cast(short, __float2bfloat16(lv[j & 3][2 + (j >> 2)]));
        }
        *(bf16x8*)(dst)      = lo;                  // ch [16g, 16g+8)
        *(bf16x8*)(dst + 16) = hi;                  // ch [16g+8, 16g+16)
    }
    #pragma unroll
    for (int m = 0; m < 4; ++m)
        #pragma unroll
        for (int qq = 0; qq < 4; ++qq) {
            float v = csum[m][qq];
            v += __shfl_xor(v, 1, 64);
            v += __shfl_xor(v, 2, 64);
            v += __shfl_xor(v, 4, 64);
            v += __shfl_xor(v, 8, 64);
            if (n16 == 0) atomicAdd(&sco[g * 16 + qq * 4 + m], v);
        }
    __syncthreads();
    if (tid < 64) atomicAdd(poolc + b * CATC + catbase + tid, sco[tid]);
}

// merged 3-branch dispatch: 1536 blocks 1D, XCD-banded mapping.
__global__ __launch_bounds__(512, 4)
void conv_branch3(const bf16* __restrict__ xT,
                  const bf16* __restrict__ aggF1, const bf16* __restrict__ aggF2,
                  const bf16* __restrict__ aggF3,
                  bf16* __restrict__ catT, float* __restrict__ poolc)
{
    constexpr int SCOO = 46080;                  // max X region (DIL4: 45 segs)
    __shared__ __align__(1024) char lds[SCOO + 256];
    float* sco = (float*)(lds + SCOO);

    const int bid  = blockIdx.x;
    const int xcd  = bid & 7;
    const int j    = bid >> 3;                   // 0..191
    const int b    = 2 * xcd + (j >= 96 ? 1 : 0);
    const int u    = j % 96;
    const int band = u / 24;                     // 0..3 (32-row band)
    const int v    = u % 24;
    const int br   = v % 3;
    const int t2   = v / 3;                      // 0..7
    const int wt   = t2 & 1;
    const int hb   = band * 4 + (t2 >> 1);       // hb in {4band..4band+3} for ALL dilations

    if (br == 0)
        conv_core<1, 64>(b, hb, wt, xT, XH, XW, XPAD, aggF1, catT, 0,   poolc, lds, sco);
    else if (br == 1)
        conv_core<2, 64>(b, hb, wt, xT, XH, XW, XPAD, aggF2, catT, 64,  poolc, lds, sco);
    else
        conv_core<4, 64>(b, hb, wt, xT, XH, XW, XPAD, aggF3, catT, 128, poolc, lds, sco);
}

// ---------------- final conv + residual: 2 rows per wave (halved bytes/MFMA) ----------------
// 256 threads = 4 waves; block = 64 co x 8 rows x 64 w; wave = 2 rows.
// X: single buffer, 10 rows x 66 slots g-major = 41.3 KB -> 2 blocks/CU at <=256 VGPR.
// Per wave per chunk: 36 A-loads + 48 B ds_reads feed 288 MFMAs (vs 36+36 -> 144).
#define FF_ROWB 4224                 // 66 slots * 64 B
#define FF_XBY  42240                // 10 rows
#define FF_XSEG 42

__global__ __launch_bounds__(256, 2)
void conv_final(const bf16* __restrict__ catT, const bf16* __restrict__ aggFt,
                const float* __restrict__ x, float* __restrict__ out)
{
    __shared__ __align__(1024) char lds[FF_XSEG * 1024];

    const int bid = blockIdx.x;                  // 512 blocks, XCD-banded
    const int xcd = bid & 7;
    const int j   = bid >> 3;                    // 0..63
    const int b   = 2 * xcd + (j >= 32 ? 1 : 0);
    const int u   = j & 31;
    const int wt  = u & 1;
    const int hb  = u >> 1;                      // 0..15 (8-row groups)

    const int tid  = threadIdx.x;
    const int wv   = tid >> 6;                   // 0..3, wave owns rows {2wv, 2wv+1}
    const int lane = tid & 63;
    const int n16  = lane & 15;
    const int g    = lane >> 4;

    const char* inB = (const char*)catT;
    const char* awB = (const char*)aggFt + (size_t)b * (6 * 36864);

    // B base per (nt,kw); row offset rr*FF_ROWB added as unroll-constant
    int baddr[12];
    #pragma unroll
    for (int nt = 0; nt < 4; ++nt)
        #pragma unroll
        for (int kw = 0; kw < 3; ++kw)
            baddr[nt*3+kw] = (2 * wv) * FF_ROWB + g * (66 * 16) + (nt * 16 + n16 + kw) * 16;

    int xoff[11];
    #pragma unroll
    for (int t = 0; t < 11; ++t) {
        int i = wv + 4 * t;
        xoff[t] = 0;
        if (i < FF_XSEG) {
            int o = i * 1024 + lane * 16;
            if (o < FF_XBY) {
                int row  = o / FF_ROWB;
                int rem  = o - row * FF_ROWB;
                int g2   = rem / (66 * 16);
                int slot = (rem - g2 * (66 * 16)) >> 4;
                int h_in = hb * 8 + row - 1;
                xoff[t] = ((b * CHH + CPAD + h_in) * CWD + (CPAD + wt * 64 - 1 + slot)) * (CATC * 2)
                          + g2 * 16;
            }
        }
    }

    auto stage = [&](int c) {
        #pragma unroll
        for (int t = 0; t < 11; ++t) {
            int i = wv + 4 * t;
            if (i >= FF_XSEG) break;
            __builtin_amdgcn_global_load_lds(
                (const __attribute__((address_space(1))) void*)(inB + (size_t)(xoff[t] + c * 64)),
                (__attribute__((address_space(3))) void*)(lds + i * 1024), 16, 0, 0);
        }
    };

    f32x4 acc[2][4][4];
    #pragma unroll
    for (int orr = 0; orr < 2; ++orr)
        #pragma unroll
        for (int nt = 0; nt < 4; ++nt)
            #pragma unroll
            for (int m = 0; m < 4; ++m) { f32x4 z = {0.f,0.f,0.f,0.f}; acc[orr][nt][m] = z; }

    for (int c = 0; c < 6; ++c) {
        stage(c);
        __syncthreads();
        const char* awC = awB + (size_t)c * 36864 + (size_t)lane * 16;
        #pragma unroll
        for (int kw = 0; kw < 3; ++kw) {
            bf16x8 a[3][4];
            #pragma unroll
            for (int kh = 0; kh < 3; ++kh)
                #pragma unroll
                for (int m = 0; m < 4; ++m)
                    a[kh][m] = *(const bf16x8*)(awC + (size_t)(((kh * 3 + kw) * 4 + m) * 1024));
            #pragma unroll
            for (int nt = 0; nt < 4; ++nt) {
                bf16x8 bfr[4];
                #pragma unroll
                for (int rr = 0; rr < 4; ++rr)
                    bfr[rr] = *(const bf16x8*)(lds + baddr[nt * 3 + kw] + rr * FF_ROWB);
                #pragma unroll
                for (int kh = 0; kh < 3; ++kh)
                    #pragma unroll
                    for (int orr = 0; orr < 2; ++orr)
                        #pragma unroll
                        for (int m = 0; m < 4; ++m)
                            acc[orr][nt][m] = __builtin_amdgcn_mfma_f32_16x16x32_bf16(
                                a[kh][m], bfr[orr + kh], acc[orr][nt][m], 0, 0, 0);
            }
        }
        __syncthreads();
    }

    #pragma unroll
    for (int orr = 0; orr < 2; ++orr) {
        const int h_out = hb * 8 + 2 * wv + orr;
        #pragma unroll
        for (int nt = 0; nt < 4; ++nt) {
            int w_out = wt * 64 + nt * 16 + n16;
            #pragma unroll
            for (int m = 0; m < 4; ++m) {
                int co = m * 16 + g * 4;
                size_t base = (((size_t)b * 64 + co) * HH + h_out) * WW + w_out;
                #pragma unroll
                for (int qq = 0; qq < 4; ++qq) {
                    size_t idx = base + (size_t)qq * HWSZ;
                    out[idx] = x[idx] + acc[orr][nt][m][qq];
                }
            }
        }
    }
}

// ---------------- launch ----------------
extern "C" void kernel_launch(void* const* d_in, const int* in_sizes, int n_in,
                              void* d_out, int out_size, void* d_ws, size_t ws_size,
                              hipStream_t stream) {
    const float* x      = (const float*)d_in[0];
    const float* w1     = (const float*)d_in[1];
    const float* fc1_1  = (const float*)d_in[2];
    const float* fc2w_1 = (const float*)d_in[3];
    const float* fc2b_1 = (const float*)d_in[4];
    const float* w2     = (const float*)d_in[5];
    const float* fc1_2  = (const float*)d_in[6];
    const float* fc2w_2 = (const float*)d_in[7];
    const float* fc2b_2 = (const float*)d_in[8];
    const float* w3     = (const float*)d_in[9];
    const float* fc1_3  = (const float*)d_in[10];
    const float* fc2w_3 = (const float*)d_in[11];
    const float* fc2b_3 = (const float*)d_in[12];
    const float* wt     = (const float*)d_in[13];
    const float* fc1_t  = (const float*)d_in[14];
    const float* fc2w_t = (const float*)d_in[15];
    const float* fc2b_t = (const float*)d_in[16];
    float* out = (float*)d_out;
    (void)in_sizes; (void)n_in; (void)out_size; (void)ws_size;

    char* ws = (char*)d_ws;
    auto alloc = [&](size_t bytes) { char* p = ws; ws += (bytes + 255) & ~(size_t)255; return p; };

    bf16*  aggF1   = (bf16*)alloc((size_t)BB * 18 * 4096);
    bf16*  aggF2   = (bf16*)alloc((size_t)BB * 18 * 4096);
    bf16*  aggF3   = (bf16*)alloc((size_t)BB * 18 * 4096);
    bf16*  aggFt   = (bf16*)alloc((size_t)BB * 54 * 4096);
    float* pooledx = (float*)alloc(BB * 64 * 4);
    float* pooledc = (float*)alloc(BB * 192 * 4);
    float* att1    = (float*)alloc(BB * 4 * 4);
    float* att2    = (float*)alloc(BB * 4 * 4);
    float* att3    = (float*)alloc(BB * 4 * 4);
    float* attt    = (float*)alloc(BB * 4 * 4);
    alloc(65536);                                            // guard
    const size_t XT_BYTES  = (size_t)BB * XH * XW * 64 * 2;
    bf16* xT   = (bf16*)alloc(XT_BYTES);
    alloc(65536);                                            // guard
    const size_t CAT_BYTES = (size_t)BB * CHH * CWD * CATC * 2;
    bf16* catT = (bf16*)alloc(CAT_BYTES);
    alloc(65536);                                            // guard

    // border + pooled zeroing, one launch
    init_borders<<<dim3(1056, 2), 256, 0, stream>>>(xT, catT, pooledx, pooledc);

    transpose_pad_pool_x<<<dim3(128, 16), 256, 0, stream>>>(x, xT, pooledx);

    attention3<<<dim3(16, 3), 64, 0, stream>>>(pooledx,
        fc1_1, fc2w_1, fc2b_1, att1,
        fc1_2, fc2w_2, fc2b_2, att2,
        fc1_3, fc2w_3, fc2b_3, att3);

    aggw_frag3<<<dim3(64, 16, 3), 256, 0, stream>>>(w1, att1, aggF1,
                                                    w2, att2, aggF2,
                                                    w3, att3, aggF3);

    conv_branch3<<<1536, 512, 0, stream>>>(xT, aggF1, aggF2, aggF3, catT, pooledc);

    attention_one<<<16, 64, 0, stream>>>(pooledc, CATC, fc1_t, 49, fc2w_t, fc2b_t, attt);
    aggw_frag_t<<<dim3(64, 16), 256, 0, stream>>>(wt, attt, aggFt);

    conv_final<<<512, 256, 0, stream>>>(catT, aggFt, x, out);
}

// Round 19
// 210.149 us; speedup vs baseline: 1.0982x; 1.0436x over previous
//
#include <hip/hip_runtime.h>
#include <hip/hip_bf16.h>

typedef __hip_bfloat16 bf16;
typedef __attribute__((ext_vector_type(4))) float f32x4;
typedef __attribute__((ext_vector_type(8))) short bf16x8;
typedef __attribute__((ext_vector_type(4))) short s16x4;

#define BB 16
#define HH 128
#define WW 128
#define HWSZ (HH*WW)
// xT: [16][136][136][64] bf16, pad 4
#define XH 136
#define XW 136
#define XPAD 4
// catT: [16][130][130][192] bf16, pad 1
#define CHH 130
#define CWD 130
#define CPAD 1
#define CATC 192

// ---------------- zero pad borders + pooled accumulators (one launch) ----------------
__device__ __forceinline__ void zero_border_body(bf16* __restrict__ base, int HP, int WP,
                                                 int PAD, int Cdim, int slots)
{
    int cg8 = Cdim >> 3;
    int per_b = slots * cg8;
    int idx = blockIdx.x * 256 + threadIdx.x;
    if (idx >= BB * per_b) return;
    int b = idx / per_b;
    int rem = idx - b * per_b;
    int slot = rem / cg8;
    int cg = rem - slot * cg8;
    int top = PAD * WP;
    int h, w;
    if (slot < top)            { h = slot / WP;            w = slot % WP; }
    else if (slot < 2 * top)   { int s = slot - top;       h = HP - PAD + s / WP; w = s % WP; }
    else {
        int s = slot - 2 * top;
        int row = s / (2 * PAD), t = s - row * (2 * PAD);
        h = PAD + row;
        w = (t < PAD) ? t : (WP - 2 * PAD + t);
    }
    bf16x8 z = {0,0,0,0,0,0,0,0};
    *(bf16x8*)(base + (((size_t)b * HP + h) * WP + w) * Cdim + cg * 8) = z;
}

__global__ void init_borders(bf16* __restrict__ xT, bf16* __restrict__ catT,
                             float* __restrict__ pooledx, float* __restrict__ pooledc)
{
    if (blockIdx.y == 0) {
        if (blockIdx.x == 0) {      // also zero pooled accumulators
            for (int i = threadIdx.x; i < BB * 64;   i += 256) pooledx[i] = 0.f;
            for (int i = threadIdx.x; i < BB * CATC; i += 256) pooledc[i] = 0.f;
        }
        zero_border_body(xT,   XH,  XW,  XPAD, 64,   2112);
    } else {
        zero_border_body(catT, CHH, CWD, CPAD, CATC, 516);
    }
}

// ---------------- LDS-tiled transpose + pad x -> bf16 channel-fast, fused pool ----------------
__global__ __launch_bounds__(256)
void transpose_pad_pool_x(const float* __restrict__ x, bf16* __restrict__ xT,
                          float* __restrict__ pooledx)
{
    __shared__ float tile[128 * 65];
    const int h = blockIdx.x, b = blockIdx.y;
    const int t = threadIdx.x;
    const int w  = t & 127;
    const int chalf = t >> 7;            // 0/1

    const float* xb = x + (((size_t)b * 64) * HH + h) * WW + w;
    #pragma unroll
    for (int it = 0; it < 32; ++it) {
        int c = it * 2 + chalf;
        tile[w * 65 + c] = xb[(size_t)c * HWSZ];
    }
    __syncthreads();

    bf16* dst = xT + (((size_t)b * XH + (h + XPAD)) * XW + XPAD) * 64;
    #pragma unroll
    for (int it = 0; it < 4; ++it) {
        int v  = t + it * 256;           // 0..1023
        int ww = v >> 3;
        int c0 = (v & 7) * 8;
        const float* src = tile + ww * 65 + c0;
        bf16x8 pk;
        #pragma unroll
        for (int j = 0; j < 8; ++j)
            pk[j] = __builtin_bit_cast(short, __float2bfloat16(src[j]));
        *(bf16x8*)(dst + (size_t)ww * 64 + c0) = pk;
    }

    if (t < 64) {
        float s = 0.f;
        #pragma unroll 4
        for (int ww = 0; ww < 128; ++ww) s += tile[ww * 65 + t];
        atomicAdd(pooledx + b * 64 + t, s);
    }
}

// ---------------- attention MLP body ----------------
__device__ __forceinline__ void attn_body(int b, const float* pooled, int Cin,
                                          const float* fc1, int hid,
                                          const float* fc2w, const float* fc2b,
                                          float* att, float* sp, float* sh, float* slg)
{
    for (int c = threadIdx.x; c < Cin; c += 64) sp[c] = pooled[b * Cin + c];
    __syncthreads();
    int j = threadIdx.x;
    if (j < hid) {
        float s = 0.f;
        const float4* f4 = (const float4*)(fc1 + (size_t)j * Cin);
        for (int c4 = 0; c4 < Cin / 4; ++c4) {
            float4 v = f4[c4];
            s += v.x * sp[c4*4+0] + v.y * sp[c4*4+1] + v.z * sp[c4*4+2] + v.w * sp[c4*4+3];
        }
        sh[j] = s > 0.f ? s * (1.0f / 16384.0f) : 0.f;   // fold 1/HW
    }
    __syncthreads();
    int k = threadIdx.x;
    if (k < 4) {
        float s = fc2b[k];
        for (int jj = 0; jj < hid; ++jj) s += fc2w[k * hid + jj] * sh[jj];
        slg[k] = s * (1.0f / 34.0f);
    }
    __syncthreads();
    if (threadIdx.x == 0) {
        float m = fmaxf(fmaxf(slg[0], slg[1]), fmaxf(slg[2], slg[3]));
        float e0 = expf(slg[0]-m), e1 = expf(slg[1]-m), e2 = expf(slg[2]-m), e3 = expf(slg[3]-m);
        float inv = 1.0f / (e0+e1+e2+e3);
        att[b*4+0] = e0*inv; att[b*4+1] = e1*inv; att[b*4+2] = e2*inv; att[b*4+3] = e3*inv;
    }
}

__global__ void attention3(const float* __restrict__ pooled,
                           const float* f1a, const float* f2a, const float* ba, float* aa,
                           const float* f1b, const float* f2b, const float* bb, float* ab,
                           const float* f1c, const float* f2c, const float* bc, float* ac)
{
    __shared__ float sp[192], sh[64], slg[4];
    int br = blockIdx.y;
    const float* fc1  = br == 0 ? f1a : br == 1 ? f1b : f1c;
    const float* fc2w = br == 0 ? f2a : br == 1 ? f2b : f2c;
    const float* fc2b = br == 0 ? ba  : br == 1 ? bb  : bc;
    float* att        = br == 0 ? aa  : br == 1 ? ab  : ac;
    attn_body(blockIdx.x, pooled, 64, fc1, 17, fc2w, fc2b, att, sp, sh, slg);
}

__global__ void attention_one(const float* __restrict__ pooled, int Cin,
                              const float* __restrict__ fc1, int hid,
                              const float* __restrict__ fc2w,
                              const float* __restrict__ fc2b, float* __restrict__ att)
{
    __shared__ float sp[192], sh[64], slg[4];
    attn_body(blockIdx.x, pooled, Cin, fc1, hid, fc2w, fc2b, att, sp, sh, slg);
}

// ---------------- aggregate weights -> bf16, MFMA A-fragment order ----------------
// Slot layout: [b][s = chunk*9+tap][m 4][lane 64][j 8] bf16.
// PERM=false: slot (m,l15) holds logical channel co = m*16 + l15 (final conv).
// PERM=true:  slot (m,l15) holds logical channel co = l15*4 + m (branches).
template<int CIN, bool PERM>
__device__ __forceinline__ void aggw_body(const float* __restrict__ w,
                                          const float* __restrict__ att,
                                          bf16* __restrict__ out, float* wl)
{
    constexpr int C9 = CIN * 9;
    constexpr int NS = (CIN / 32) * 9;
    const int co = blockIdx.x, b = blockIdx.y;
    const int src = PERM ? ((co & 15) * 4 + (co >> 4)) : co;
    for (int i = threadIdx.x; i < 4 * C9; i += 256) {
        int k = i / C9, rem = i - k * C9;
        wl[i] = w[((size_t)k * 64 + src) * C9 + rem];
    }
    __syncthreads();
    float a0 = att[b*4+0], a1 = att[b*4+1], a2 = att[b*4+2], a3 = att[b*4+3];
    const int m = co >> 4, l15 = co & 15;
    char* ob = (char*)out + (size_t)b * NS * 4096;
    for (int t = threadIdx.x; t < NS * 32; t += 256) {
        int s = t >> 5, rem = t & 31;
        int gg = rem >> 3, j = rem & 7;
        int chunk = s / 9, tap = s - chunk * 9;
        int ci = chunk * 32 + gg * 8 + j;
        float v = a0 * wl[ci*9 + tap] + a1 * wl[C9 + ci*9 + tap]
                + a2 * wl[2*C9 + ci*9 + tap] + a3 * wl[3*C9 + ci*9 + tap];
        *(bf16*)(ob + ((size_t)((s*4 + m) * 64 + (gg*16 + l15))) * 16 + j * 2) = __float2bfloat16(v);
    }
}

// fused: 3 branch weight aggregations, grid (64, 16, 3)
__global__ void aggw_frag3(const float* __restrict__ w1, const float* __restrict__ att1, bf16* o1,
                           const float* __restrict__ w2, const float* __restrict__ att2, bf16* o2,
                           const float* __restrict__ w3, const float* __restrict__ att3, bf16* o3)
{
    __shared__ float wl[4 * 64 * 9];
    int z = blockIdx.z;
    if (z == 0)      aggw_body<64, true>(w1, att1, o1, wl);
    else if (z == 1) aggw_body<64, true>(w2, att2, o2, wl);
    else             aggw_body<64, true>(w3, att3, o3, wl);
}

__global__ void aggw_frag_t(const float* __restrict__ w, const float* __restrict__ att,
                            bf16* __restrict__ out)
{
    __shared__ float wl[4 * 192 * 9];
    aggw_body<192, false>(w, att, out, wl);
}

// ---------------- branch conv core: 2 dil-strided rows per wave ----------------
// 256 threads = 4 waves; block = 64 co x 8 dil-strided rows x 64 w; wave = rows {2wv,2wv+1}.
// X LDS (g-major): [row 10][g 4][slot SLOTS][16B]. A from global (L2).
// Per wave per chunk: 36 A-loads + 48 B ds_reads feed 288 MFMAs.
template<int DIL, int CIN>
__device__ __forceinline__ void conv_core2(
    int b, int hb, int wt,
    const bf16* __restrict__ inT, int HPd, int WPd, int PAD,
    const bf16* __restrict__ aggwF,
    bf16* __restrict__ catT, int catbase, float* __restrict__ poolc,
    char* lds, float* sco)
{
    constexpr int NCHUNK = CIN / 32;
    constexpr int SLOTS  = 64 + 2 * DIL;
    constexpr int ROWB   = SLOTS * 64;
    constexpr int XBYTES = 10 * ROWB;
    constexpr int XSEG   = (XBYTES + 1023) / 1024;
    constexpr int ABYTES = 36864;
    constexpr int MAXT   = (XSEG + 3) / 4;

    const int r  = hb % DIL;
    const int q  = hb / DIL;
    const int tid  = threadIdx.x;
    const int wv   = tid >> 6;               // 0..3
    const int lane = tid & 63;
    const int n16  = lane & 15;
    const int g    = lane >> 4;

    const char* inB = (const char*)inT;
    const char* awB = (const char*)aggwF + (size_t)b * (NCHUNK * ABYTES);

    if (tid < 64) sco[tid] = 0.f;

    int baddr[12];
    #pragma unroll
    for (int nt = 0; nt < 4; ++nt)
        #pragma unroll
        for (int kw = 0; kw < 3; ++kw)
            baddr[nt*3+kw] = (2 * wv) * ROWB + g * (SLOTS * 16)
                             + (nt * 16 + n16 + kw * DIL) * 16;

    int xoff[MAXT];
    #pragma unroll
    for (int t = 0; t < MAXT; ++t) {
        int i = wv + 4 * t;
        xoff[t] = 0;
        if (i < XSEG) {
            int o = i * 1024 + lane * 16;
            if (o < XBYTES) {
                int row  = o / ROWB;
                int rem  = o - row * ROWB;
                int g2   = rem / (SLOTS * 16);
                int slot = (rem - g2 * (SLOTS * 16)) >> 4;
                int h_in = (q * 8 + row - 1) * DIL + r;
                xoff[t] = ((b * HPd + PAD + h_in) * WPd + (PAD + wt * 64 - DIL + slot)) * (CIN * 2)
                          + g2 * 16;
            }
        }
    }

    auto stage = [&](int c) {
        #pragma unroll
        for (int t = 0; t < MAXT; ++t) {
            int i = wv + 4 * t;
            if (i >= XSEG) break;
            __builtin_amdgcn_global_load_lds(
                (const __attribute__((address_space(1))) void*)(inB + (size_t)(xoff[t] + c * 64)),
                (__attribute__((address_space(3))) void*)(lds + i * 1024), 16, 0, 0);
        }
    };

    f32x4 acc[2][4][4];
    #pragma unroll
    for (int orr = 0; orr < 2; ++orr)
        #pragma unroll
        for (int nt = 0; nt < 4; ++nt)
            #pragma unroll
            for (int m = 0; m < 4; ++m) { f32x4 z = {0.f,0.f,0.f,0.f}; acc[orr][nt][m] = z; }

    for (int c = 0; c < NCHUNK; ++c) {
        stage(c);
        __syncthreads();
        const char* awC = awB + (size_t)c * ABYTES + (size_t)lane * 16;
        #pragma unroll
        for (int kw = 0; kw < 3; ++kw) {
            bf16x8 a[3][4];
            #pragma unroll
            for (int kh = 0; kh < 3; ++kh)
                #pragma unroll
                for (int m = 0; m < 4; ++m)
                    a[kh][m] = *(const bf16x8*)(awC + (size_t)(((kh * 3 + kw) * 4 + m) * 1024));
            #pragma unroll
            for (int nt = 0; nt < 4; ++nt) {
                bf16x8 bfr[4];
                #pragma unroll
                for (int rr = 0; rr < 4; ++rr)
                    bfr[rr] = *(const bf16x8*)(lds + baddr[nt * 3 + kw] + rr * ROWB);
                #pragma unroll
                for (int kh = 0; kh < 3; ++kh)
                    #pragma unroll
                    for (int orr = 0; orr < 2; ++orr)
                        #pragma unroll
                        for (int m = 0; m < 4; ++m)
                            acc[orr][nt][m] = __builtin_amdgcn_mfma_f32_16x16x32_bf16(
                                a[kh][m], bfr[orr + kh], acc[orr][nt][m], 0, 0, 0);
            }
        }
        __syncthreads();
    }

    // ---- epilogue: leaky -> catT (coalesced, PERM'd) + pooled sums ----
    float csum[4][4];
    #pragma unroll
    for (int m = 0; m < 4; ++m)
        #pragma unroll
        for (int qq = 0; qq < 4; ++qq) csum[m][qq] = 0.f;
    #pragma unroll
    for (int orr = 0; orr < 2; ++orr) {
        const int h_out = (q * 8 + 2 * wv + orr) * DIL + r;
        #pragma unroll
        for (int nt = 0; nt < 4; ++nt) {
            int w_out = wt * 64 + nt * 16 + n16;
            char* dst = (char*)(catT + (((size_t)b * CHH + (CPAD + h_out)) * CWD + (CPAD + w_out)) * CATC
                                + catbase) + g * 32;
            float lv[4][4];
            #pragma unroll
            for (int m = 0; m < 4; ++m)
                #pragma unroll
                for (int qq = 0; qq < 4; ++qq) {
                    float v = acc[orr][nt][m][qq];
                    v = v >= 0.f ? v : 0.1f * v;        // leaky
                    lv[m][qq] = v;
                    csum[m][qq] += v;
                }
            bf16x8 lo, hi;
            #pragma unroll
            for (int j = 0; j < 8; ++j) {
                lo[j] = __builtin_bit_cast(short, __float2bfloat16(lv[j & 3][j >> 2]));
                hi[j] = __builtin_bit_cast(short, __float2bfloat16(lv[j & 3][2 + (j >> 2)]));
            }
            *(bf16x8*)(dst)      = lo;                  // ch [16g, 16g+8)
            *(bf16x8*)(dst + 16) = hi;                  // ch [16g+8, 16g+16)
        }
    }
    #pragma unroll
    for (int m = 0; m < 4; ++m)
        #pragma unroll
        for (int qq = 0; qq < 4; ++qq) {
            float v = csum[m][qq];
            v += __shfl_xor(v, 1, 64);
            v += __shfl_xor(v, 2, 64);
            v += __shfl_xor(v, 4, 64);
            v += __shfl_xor(v, 8, 64);
            if (n16 == 0) atomicAdd(&sco[g * 16 + qq * 4 + m], v);
        }
    __syncthreads();
    if (tid < 64) atomicAdd(poolc + b * CATC + catbase + tid, sco[tid]);
}

// merged 3-branch dispatch: 1536 blocks 1D, XCD-banded mapping, 256 threads.
__global__ __launch_bounds__(256, 2)
void conv_branch3(const bf16* __restrict__ xT,
                  const bf16* __restrict__ aggF1, const bf16* __restrict__ aggF2,
                  const bf16* __restrict__ aggF3,
                  bf16* __restrict__ catT, float* __restrict__ poolc)
{
    constexpr int SCOO = 46080;                  // max X region (DIL4: 45 segs)
    __shared__ __align__(1024) char lds[SCOO + 256];
    float* sco = (float*)(lds + SCOO);

    const int bid  = blockIdx.x;
    const int xcd  = bid & 7;
    const int j    = bid >> 3;                   // 0..191
    const int b    = 2 * xcd + (j >= 96 ? 1 : 0);
    const int u    = j % 96;
    const int band = u / 24;                     // 0..3 (32-row band)
    const int v    = u % 24;
    const int br   = v % 3;
    const int t2   = v / 3;                      // 0..7
    const int wt   = t2 & 1;
    const int hb   = band * 4 + (t2 >> 1);       // hb in {4band..4band+3} for ALL dilations

    if (br == 0)
        conv_core2<1, 64>(b, hb, wt, xT, XH, XW, XPAD, aggF1, catT, 0,   poolc, lds, sco);
    else if (br == 1)
        conv_core2<2, 64>(b, hb, wt, xT, XH, XW, XPAD, aggF2, catT, 64,  poolc, lds, sco);
    else
        conv_core2<4, 64>(b, hb, wt, xT, XH, XW, XPAD, aggF3, catT, 128, poolc, lds, sco);
}

// ---------------- final conv + residual: 2 rows per wave (halved bytes/MFMA) ----------------
#define FF_ROWB 4224                 // 66 slots * 64 B
#define FF_XBY  42240                // 10 rows
#define FF_XSEG 42

__global__ __launch_bounds__(256, 2)
void conv_final(const bf16* __restrict__ catT, const bf16* __restrict__ aggFt,
                const float* __restrict__ x, float* __restrict__ out)
{
    __shared__ __align__(1024) char lds[FF_XSEG * 1024];

    const int bid = blockIdx.x;                  // 512 blocks, XCD-banded
    const int xcd = bid & 7;
    const int j   = bid >> 3;                    // 0..63
    const int b   = 2 * xcd + (j >= 32 ? 1 : 0);
    const int u   = j & 31;
    const int wt  = u & 1;
    const int hb  = u >> 1;                      // 0..15 (8-row groups)

    const int tid  = threadIdx.x;
    const int wv   = tid >> 6;                   // 0..3, wave owns rows {2wv, 2wv+1}
    const int lane = tid & 63;
    const int n16  = lane & 15;
    const int g    = lane >> 4;

    const char* inB = (const char*)catT;
    const char* awB = (const char*)aggFt + (size_t)b * (6 * 36864);

    int baddr[12];
    #pragma unroll
    for (int nt = 0; nt < 4; ++nt)
        #pragma unroll
        for (int kw = 0; kw < 3; ++kw)
            baddr[nt*3+kw] = (2 * wv) * FF_ROWB + g * (66 * 16) + (nt * 16 + n16 + kw) * 16;

    int xoff[11];
    #pragma unroll
    for (int t = 0; t < 11; ++t) {
        int i = wv + 4 * t;
        xoff[t] = 0;
        if (i < FF_XSEG) {
            int o = i * 1024 + lane * 16;
            if (o < FF_XBY) {
                int row  = o / FF_ROWB;
                int rem  = o - row * FF_ROWB;
                int g2   = rem / (66 * 16);
                int slot = (rem - g2 * (66 * 16)) >> 4;
                int h_in = hb * 8 + row - 1;
                xoff[t] = ((b * CHH + CPAD + h_in) * CWD + (CPAD + wt * 64 - 1 + slot)) * (CATC * 2)
                          + g2 * 16;
            }
        }
    }

    auto stage = [&](int c) {
        #pragma unroll
        for (int t = 0; t < 11; ++t) {
            int i = wv + 4 * t;
            if (i >= FF_XSEG) break;
            __builtin_amdgcn_global_load_lds(
                (const __attribute__((address_space(1))) void*)(inB + (size_t)(xoff[t] + c * 64)),
                (__attribute__((address_space(3))) void*)(lds + i * 1024), 16, 0, 0);
        }
    };

    f32x4 acc[2][4][4];
    #pragma unroll
    for (int orr = 0; orr < 2; ++orr)
        #pragma unroll
        for (int nt = 0; nt < 4; ++nt)
            #pragma unroll
            for (int m = 0; m < 4; ++m) { f32x4 z = {0.f,0.f,0.f,0.f}; acc[orr][nt][m] = z; }

    for (int c = 0; c < 6; ++c) {
        stage(c);
        __syncthreads();
        const char* awC = awB + (size_t)c * 36864 + (size_t)lane * 16;
        #pragma unroll
        for (int kw = 0; kw < 3; ++kw) {
            bf16x8 a[3][4];
            #pragma unroll
            for (int kh = 0; kh < 3; ++kh)
                #pragma unroll
                for (int m = 0; m < 4; ++m)
                    a[kh][m] = *(const bf16x8*)(awC + (size_t)(((kh * 3 + kw) * 4 + m) * 1024));
            #pragma unroll
            for (int nt = 0; nt < 4; ++nt) {
                bf16x8 bfr[4];
                #pragma unroll
                for (int rr = 0; rr < 4; ++rr)
                    bfr[rr] = *(const bf16x8*)(lds + baddr[nt * 3 + kw] + rr * FF_ROWB);
                #pragma unroll
                for (int kh = 0; kh < 3; ++kh)
                    #pragma unroll
                    for (int orr = 0; orr < 2; ++orr)
                        #pragma unroll
                        for (int m = 0; m < 4; ++m)
                            acc[orr][nt][m] = __builtin_amdgcn_mfma_f32_16x16x32_bf16(
                                a[kh][m], bfr[orr + kh], acc[orr][nt][m], 0, 0, 0);
            }
        }
        __syncthreads();
    }

    #pragma unroll
    for (int orr = 0; orr < 2; ++orr) {
        const int h_out = hb * 8 + 2 * wv + orr;
        #pragma unroll
        for (int nt = 0; nt < 4; ++nt) {
            int w_out = wt * 64 + nt * 16 + n16;
            #pragma unroll
            for (int m = 0; m < 4; ++m) {
                int co = m * 16 + g * 4;
                size_t base = (((size_t)b * 64 + co) * HH + h_out) * WW + w_out;
                #pragma unroll
                for (int qq = 0; qq < 4; ++qq) {
                    size_t idx = base + (size_t)qq * HWSZ;
                    out[idx] = x[idx] + acc[orr][nt][m][qq];
                }
            }
        }
    }
}

// ---------------- launch ----------------
extern "C" void kernel_launch(void* const* d_in, const int* in_sizes, int n_in,
                              void* d_out, int out_size, void* d_ws, size_t ws_size,
                              hipStream_t stream) {
    const float* x      = (const float*)d_in[0];
    const float* w1     = (const float*)d_in[1];
    const float* fc1_1  = (const float*)d_in[2];
    const float* fc2w_1 = (const float*)d_in[3];
    const float* fc2b_1 = (const float*)d_in[4];
    const float* w2     = (const float*)d_in[5];
    const float* fc1_2  = (const float*)d_in[6];
    const float* fc2w_2 = (const float*)d_in[7];
    const float* fc2b_2 = (const float*)d_in[8];
    const float* w3     = (const float*)d_in[9];
    const float* fc1_3  = (const float*)d_in[10];
    const float* fc2w_3 = (const float*)d_in[11];
    const float* fc2b_3 = (const float*)d_in[12];
    const float* wt     = (const float*)d_in[13];
    const float* fc1_t  = (const float*)d_in[14];
    const float* fc2w_t = (const float*)d_in[15];
    const float* fc2b_t = (const float*)d_in[16];
    float* out = (float*)d_out;
    (void)in_sizes; (void)n_in; (void)out_size; (void)ws_size;

    char* ws = (char*)d_ws;
    auto alloc = [&](size_t bytes) { char* p = ws; ws += (bytes + 255) & ~(size_t)255; return p; };

    bf16*  aggF1   = (bf16*)alloc((size_t)BB * 18 * 4096);
    bf16*  aggF2   = (bf16*)alloc((size_t)BB * 18 * 4096);
    bf16*  aggF3   = (bf16*)alloc((size_t)BB * 18 * 4096);
    bf16*  aggFt   = (bf16*)alloc((size_t)BB * 54 * 4096);
    float* pooledx = (float*)alloc(BB * 64 * 4);
    float* pooledc = (float*)alloc(BB * 192 * 4);
    float* att1    = (float*)alloc(BB * 4 * 4);
    float* att2    = (float*)alloc(BB * 4 * 4);
    float* att3    = (float*)alloc(BB * 4 * 4);
    float* attt    = (float*)alloc(BB * 4 * 4);
    alloc(65536);                                            // guard
    const size_t XT_BYTES  = (size_t)BB * XH * XW * 64 * 2;
    bf16* xT   = (bf16*)alloc(XT_BYTES);
    alloc(65536);                                            // guard
    const size_t CAT_BYTES = (size_t)BB * CHH * CWD * CATC * 2;
    bf16* catT = (bf16*)alloc(CAT_BYTES);
    alloc(65536);                                            // guard

    // border + pooled zeroing, one launch
    init_borders<<<dim3(1056, 2), 256, 0, stream>>>(xT, catT, pooledx, pooledc);

    transpose_pad_pool_x<<<dim3(128, 16), 256, 0, stream>>>(x, xT, pooledx);

    attention3<<<dim3(16, 3), 64, 0, stream>>>(pooledx,
        fc1_1, fc2w_1, fc2b_1, att1,
        fc1_2, fc2w_2, fc2b_2, att2,
        fc1_3, fc2w_3, fc2b_3, att3);

    aggw_frag3<<<dim3(64, 16, 3), 256, 0, stream>>>(w1, att1, aggF1,
                                                    w2, att2, aggF2,
                                                    w3, att3, aggF3);

    conv_branch3<<<1536, 256, 0, stream>>>(xT, aggF1, aggF2, aggF3, catT, pooledc);

    attention_one<<<16, 64, 0, stream>>>(pooledc, CATC, fc1_t, 49, fc2w_t, fc2b_t, attt);
    aggw_frag_t<<<dim3(64, 16), 256, 0, stream>>>(wt, attt, aggFt);

    conv_final<<<512, 256, 0, stream>>>(catT, aggFt, x, out);
}

// Round 20
// 208.877 us; speedup vs baseline: 1.1049x; 1.0061x over previous
//
#include <hip/hip_runtime.h>
#include <hip/hip_bf16.h>

typedef __hip_bfloat16 bf16;
typedef __attribute__((ext_vector_type(4))) float f32x4;
typedef __attribute__((ext_vector_type(8))) short bf16x8;
typedef __attribute__((ext_vector_type(4))) short s16x4;

#define BB 16
#define HH 128
#define WW 128
#define HWSZ (HH*WW)
// xT: [16][136][136][64] bf16, pad 4
#define XH 136
#define XW 136
#define XPAD 4
// catT: [16][130][130][192] bf16, pad 1
#define CHH 130
#define CWD 130
#define CPAD 1
#define CATC 192

// ---------------- zero pad borders + pooled accumulators (one launch) ----------------
__device__ __forceinline__ void zero_border_body(bf16* __restrict__ base, int HP, int WP,
                                                 int PAD, int Cdim, int slots)
{
    int cg8 = Cdim >> 3;
    int per_b = slots * cg8;
    int idx = blockIdx.x * 256 + threadIdx.x;
    if (idx >= BB * per_b) return;
    int b = idx / per_b;
    int rem = idx - b * per_b;
    int slot = rem / cg8;
    int cg = rem - slot * cg8;
    int top = PAD * WP;
    int h, w;
    if (slot < top)            { h = slot / WP;            w = slot % WP; }
    else if (slot < 2 * top)   { int s = slot - top;       h = HP - PAD + s / WP; w = s % WP; }
    else {
        int s = slot - 2 * top;
        int row = s / (2 * PAD), t = s - row * (2 * PAD);
        h = PAD + row;
        w = (t < PAD) ? t : (WP - 2 * PAD + t);
    }
    bf16x8 z = {0,0,0,0,0,0,0,0};
    *(bf16x8*)(base + (((size_t)b * HP + h) * WP + w) * Cdim + cg * 8) = z;
}

__global__ void init_borders(bf16* __restrict__ xT, bf16* __restrict__ catT,
                             float* __restrict__ pooledx, float* __restrict__ pooledc)
{
    if (blockIdx.y == 0) {
        if (blockIdx.x == 0) {      // also zero pooled accumulators
            for (int i = threadIdx.x; i < BB * 64;   i += 256) pooledx[i] = 0.f;
            for (int i = threadIdx.x; i < BB * CATC; i += 256) pooledc[i] = 0.f;
        }
        zero_border_body(xT,   XH,  XW,  XPAD, 64,   2112);
    } else {
        zero_border_body(catT, CHH, CWD, CPAD, CATC, 516);
    }
}

// ---------------- LDS-tiled transpose + pad x -> bf16 channel-fast, fused pool ----------------
__global__ __launch_bounds__(256)
void transpose_pad_pool_x(const float* __restrict__ x, bf16* __restrict__ xT,
                          float* __restrict__ pooledx)
{
    __shared__ float tile[128 * 65];
    const int h = blockIdx.x, b = blockIdx.y;
    const int t = threadIdx.x;
    const int w  = t & 127;
    const int chalf = t >> 7;            // 0/1

    const float* xb = x + (((size_t)b * 64) * HH + h) * WW + w;
    #pragma unroll
    for (int it = 0; it < 32; ++it) {
        int c = it * 2 + chalf;
        tile[w * 65 + c] = xb[(size_t)c * HWSZ];
    }
    __syncthreads();

    bf16* dst = xT + (((size_t)b * XH + (h + XPAD)) * XW + XPAD) * 64;
    #pragma unroll
    for (int it = 0; it < 4; ++it) {
        int v  = t + it * 256;           // 0..1023
        int ww = v >> 3;
        int c0 = (v & 7) * 8;
        const float* src = tile + ww * 65 + c0;
        bf16x8 pk;
        #pragma unroll
        for (int j = 0; j < 8; ++j)
            pk[j] = __builtin_bit_cast(short, __float2bfloat16(src[j]));
        *(bf16x8*)(dst + (size_t)ww * 64 + c0) = pk;
    }

    if (t < 64) {
        float s = 0.f;
        #pragma unroll 4
        for (int ww = 0; ww < 128; ++ww) s += tile[ww * 65 + t];
        atomicAdd(pooledx + b * 64 + t, s);
    }
}

// ---------------- attention MLP body ----------------
__device__ __forceinline__ void attn_body(int b, const float* pooled, int Cin,
                                          const float* fc1, int hid,
                                          const float* fc2w, const float* fc2b,
                                          float* att, float* sp, float* sh, float* slg)
{
    for (int c = threadIdx.x; c < Cin; c += 64) sp[c] = pooled[b * Cin + c];
    __syncthreads();
    int j = threadIdx.x;
    if (j < hid) {
        float s = 0.f;
        const float4* f4 = (const float4*)(fc1 + (size_t)j * Cin);
        for (int c4 = 0; c4 < Cin / 4; ++c4) {
            float4 v = f4[c4];
            s += v.x * sp[c4*4+0] + v.y * sp[c4*4+1] + v.z * sp[c4*4+2] + v.w * sp[c4*4+3];
        }
        sh[j] = s > 0.f ? s * (1.0f / 16384.0f) : 0.f;   // fold 1/HW
    }
    __syncthreads();
    int k = threadIdx.x;
    if (k < 4) {
        float s = fc2b[k];
        for (int jj = 0; jj < hid; ++jj) s += fc2w[k * hid + jj] * sh[jj];
        slg[k] = s * (1.0f / 34.0f);
    }
    __syncthreads();
    if (threadIdx.x == 0) {
        float m = fmaxf(fmaxf(slg[0], slg[1]), fmaxf(slg[2], slg[3]));
        float e0 = expf(slg[0]-m), e1 = expf(slg[1]-m), e2 = expf(slg[2]-m), e3 = expf(slg[3]-m);
        float inv = 1.0f / (e0+e1+e2+e3);
        att[b*4+0] = e0*inv; att[b*4+1] = e1*inv; att[b*4+2] = e2*inv; att[b*4+3] = e3*inv;
    }
}

__global__ void attention3(const float* __restrict__ pooled,
                           const float* f1a, const float* f2a, const float* ba, float* aa,
                           const float* f1b, const float* f2b, const float* bb, float* ab,
                           const float* f1c, const float* f2c, const float* bc, float* ac)
{
    __shared__ float sp[192], sh[64], slg[4];
    int br = blockIdx.y;
    const float* fc1  = br == 0 ? f1a : br == 1 ? f1b : f1c;
    const float* fc2w = br == 0 ? f2a : br == 1 ? f2b : f2c;
    const float* fc2b = br == 0 ? ba  : br == 1 ? bb  : bc;
    float* att        = br == 0 ? aa  : br == 1 ? ab  : ac;
    attn_body(blockIdx.x, pooled, 64, fc1, 17, fc2w, fc2b, att, sp, sh, slg);
}

__global__ void attention_one(const float* __restrict__ pooled, int Cin,
                              const float* __restrict__ fc1, int hid,
                              const float* __restrict__ fc2w,
                              const float* __restrict__ fc2b, float* __restrict__ att)
{
    __shared__ float sp[192], sh[64], slg[4];
    attn_body(blockIdx.x, pooled, Cin, fc1, hid, fc2w, fc2b, att, sp, sh, slg);
}

// ---------------- aggregate weights -> bf16, MFMA A-fragment order ----------------
// Slot layout: [b][s = chunk*9+tap][m 4][lane 64][j 8] bf16.
// PERM=false: slot (m,l15) holds logical channel co = m*16 + l15 (final conv).
// PERM=true:  slot (m,l15) holds logical channel co = l15*4 + m (branches).
template<int CIN, bool PERM>
__device__ __forceinline__ void aggw_body(const float* __restrict__ w,
                                          const float* __restrict__ att,
                                          bf16* __restrict__ out, float* wl)
{
    constexpr int C9 = CIN * 9;
    constexpr int NS = (CIN / 32) * 9;
    const int co = blockIdx.x, b = blockIdx.y;
    const int src = PERM ? ((co & 15) * 4 + (co >> 4)) : co;
    for (int i = threadIdx.x; i < 4 * C9; i += 256) {
        int k = i / C9, rem = i - k * C9;
        wl[i] = w[((size_t)k * 64 + src) * C9 + rem];
    }
    __syncthreads();
    float a0 = att[b*4+0], a1 = att[b*4+1], a2 = att[b*4+2], a3 = att[b*4+3];
    const int m = co >> 4, l15 = co & 15;
    char* ob = (char*)out + (size_t)b * NS * 4096;
    for (int t = threadIdx.x; t < NS * 32; t += 256) {
        int s = t >> 5, rem = t & 31;
        int gg = rem >> 3, j = rem & 7;
        int chunk = s / 9, tap = s - chunk * 9;
        int ci = chunk * 32 + gg * 8 + j;
        float v = a0 * wl[ci*9 + tap] + a1 * wl[C9 + ci*9 + tap]
                + a2 * wl[2*C9 + ci*9 + tap] + a3 * wl[3*C9 + ci*9 + tap];
        *(bf16*)(ob + ((size_t)((s*4 + m) * 64 + (gg*16 + l15))) * 16 + j * 2) = __float2bfloat16(v);
    }
}

// fused: 3 branch weight aggregations, grid (64, 16, 3)
__global__ void aggw_frag3(const float* __restrict__ w1, const float* __restrict__ att1, bf16* o1,
                           const float* __restrict__ w2, const float* __restrict__ att2, bf16* o2,
                           const float* __restrict__ w3, const float* __restrict__ att3, bf16* o3)
{
    __shared__ float wl[4 * 64 * 9];
    int z = blockIdx.z;
    if (z == 0)      aggw_body<64, true>(w1, att1, o1, wl);
    else if (z == 1) aggw_body<64, true>(w2, att2, o2, wl);
    else             aggw_body<64, true>(w3, att3, o3, wl);
}

__global__ void aggw_frag_t(const float* __restrict__ w, const float* __restrict__ att,
                            bf16* __restrict__ out)
{
    __shared__ float wl[4 * 192 * 9];
    aggw_body<192, false>(w, att, out, wl);
}

// ---------------- branch conv core: 2 dil-strided rows per wave ----------------
// 256 threads = 4 waves; block = 64 co x 8 dil-strided rows x 64 w; wave = rows {2wv,2wv+1}.
// X LDS (g-major): [row 10][g 4][slot SLOTS][16B]. A from global (L2).
// Per wave per chunk: 36 A-loads + 48 B ds_reads feed 288 MFMAs.
template<int DIL, int CIN>
__device__ __forceinline__ void conv_core2(
    int b, int hb, int wt,
    const bf16* __restrict__ inT, int HPd, int WPd, int PAD,
    const bf16* __restrict__ aggwF,
    bf16* __restrict__ catT, int catbase, float* __restrict__ poolc,
    char* lds, float* sco)
{
    constexpr int NCHUNK = CIN / 32;
    constexpr int SLOTS  = 64 + 2 * DIL;
    constexpr int ROWB   = SLOTS * 64;
    constexpr int XBYTES = 10 * ROWB;
    constexpr int XSEG   = (XBYTES + 1023) / 1024;
    constexpr int ABYTES = 36864;
    constexpr int MAXT   = (XSEG + 3) / 4;

    const int r  = hb % DIL;
    const int q  = hb / DIL;
    const int tid  = threadIdx.x;
    const int wv   = tid >> 6;               // 0..3
    const int lane = tid & 63;
    const int n16  = lane & 15;
    const int g    = lane >> 4;

    const char* inB = (const char*)inT;
    const char* awB = (const char*)aggwF + (size_t)b * (NCHUNK * ABYTES);

    if (tid < 64) sco[tid] = 0.f;

    int baddr[12];
    #pragma unroll
    for (int nt = 0; nt < 4; ++nt)
        #pragma unroll
        for (int kw = 0; kw < 3; ++kw)
            baddr[nt*3+kw] = (2 * wv) * ROWB + g * (SLOTS * 16)
                             + (nt * 16 + n16 + kw * DIL) * 16;

    int xoff[MAXT];
    #pragma unroll
    for (int t = 0; t < MAXT; ++t) {
        int i = wv + 4 * t;
        xoff[t] = 0;
        if (i < XSEG) {
            int o = i * 1024 + lane * 16;
            if (o < XBYTES) {
                int row  = o / ROWB;
                int rem  = o - row * ROWB;
                int g2   = rem / (SLOTS * 16);
                int slot = (rem - g2 * (SLOTS * 16)) >> 4;
                int h_in = (q * 8 + row - 1) * DIL + r;
                xoff[t] = ((b * HPd + PAD + h_in) * WPd + (PAD + wt * 64 - DIL + slot)) * (CIN * 2)
                          + g2 * 16;
            }
        }
    }

    auto stage = [&](int c) {
        #pragma unroll
        for (int t = 0; t < MAXT; ++t) {
            int i = wv + 4 * t;
            if (i >= XSEG) break;
            __builtin_amdgcn_global_load_lds(
                (const __attribute__((address_space(1))) void*)(inB + (size_t)(xoff[t] + c * 64)),
                (__attribute__((address_space(3))) void*)(lds + i * 1024), 16, 0, 0);
        }
    };

    f32x4 acc[2][4][4];
    #pragma unroll
    for (int orr = 0; orr < 2; ++orr)
        #pragma unroll
        for (int nt = 0; nt < 4; ++nt)
            #pragma unroll
            for (int m = 0; m < 4; ++m) { f32x4 z = {0.f,0.f,0.f,0.f}; acc[orr][nt][m] = z; }

    for (int c = 0; c < NCHUNK; ++c) {
        stage(c);
        __syncthreads();
        const char* awC = awB + (size_t)c * ABYTES + (size_t)lane * 16;
        __builtin_amdgcn_s_setprio(1);
        #pragma unroll
        for (int kw = 0; kw < 3; ++kw) {
            bf16x8 a[3][4];
            #pragma unroll
            for (int kh = 0; kh < 3; ++kh)
                #pragma unroll
                for (int m = 0; m < 4; ++m)
                    a[kh][m] = *(const bf16x8*)(awC + (size_t)(((kh * 3 + kw) * 4 + m) * 1024));
            #pragma unroll
            for (int nt = 0; nt < 4; ++nt) {
                bf16x8 bfr[4];
                #pragma unroll
                for (int rr = 0; rr < 4; ++rr)
                    bfr[rr] = *(const bf16x8*)(lds + baddr[nt * 3 + kw] + rr * ROWB);
                #pragma unroll
                for (int kh = 0; kh < 3; ++kh)
                    #pragma unroll
                    for (int orr = 0; orr < 2; ++orr)
                        #pragma unroll
                        for (int m = 0; m < 4; ++m)
                            acc[orr][nt][m] = __builtin_amdgcn_mfma_f32_16x16x32_bf16(
                                a[kh][m], bfr[orr + kh], acc[orr][nt][m], 0, 0, 0);
            }
        }
        __builtin_amdgcn_s_setprio(0);
        __syncthreads();
    }

    // ---- epilogue: leaky -> catT (coalesced, PERM'd) + pooled sums ----
    float csum[4][4];
    #pragma unroll
    for (int m = 0; m < 4; ++m)
        #pragma unroll
        for (int qq = 0; qq < 4; ++qq) csum[m][qq] = 0.f;
    #pragma unroll
    for (int orr = 0; orr < 2; ++orr) {
        const int h_out = (q * 8 + 2 * wv + orr) * DIL + r;
        #pragma unroll
        for (int nt = 0; nt < 4; ++nt) {
            int w_out = wt * 64 + nt * 16 + n16;
            char* dst = (char*)(catT + (((size_t)b * CHH + (CPAD + h_out)) * CWD + (CPAD + w_out)) * CATC
                                + catbase) + g * 32;
            float lv[4][4];
            #pragma unroll
            for (int m = 0; m < 4; ++m)
                #pragma unroll
                for (int qq = 0; qq < 4; ++qq) {
                    float v = acc[orr][nt][m][qq];
                    v = v >= 0.f ? v : 0.1f * v;        // leaky
                    lv[m][qq] = v;
                    csum[m][qq] += v;
                }
            bf16x8 lo, hi;
            #pragma unroll
            for (int j = 0; j < 8; ++j) {
                lo[j] = __builtin_bit_cast(short, __float2bfloat16(lv[j & 3][j >> 2]));
                hi[j] = __builtin_bit_cast(short, __float2bfloat16(lv[j & 3][2 + (j >> 2)]));
            }
            *(bf16x8*)(dst)      = lo;                  // ch [16g, 16g+8)
            *(bf16x8*)(dst + 16) = hi;                  // ch [16g+8, 16g+16)
        }
    }
    #pragma unroll
    for (int m = 0; m < 4; ++m)
        #pragma unroll
        for (int qq = 0; qq < 4; ++qq) {
            float v = csum[m][qq];
            v += __shfl_xor(v, 1, 64);
            v += __shfl_xor(v, 2, 64);
            v += __shfl_xor(v, 4, 64);
            v += __shfl_xor(v, 8, 64);
            if (n16 == 0) atomicAdd(&sco[g * 16 + qq * 4 + m], v);
        }
    __syncthreads();
    if (tid < 64) atomicAdd(poolc + b * CATC + catbase + tid, sco[tid]);
}

// merged 3-branch dispatch: 1536 blocks 1D, XCD-banded mapping, 256 threads.
__global__ __launch_bounds__(256, 2)
void conv_branch3(const bf16* __restrict__ xT,
                  const bf16* __restrict__ aggF1, const bf16* __restrict__ aggF2,
                  const bf16* __restrict__ aggF3,
                  bf16* __restrict__ catT, float* __restrict__ poolc)
{
    constexpr int SCOO = 46080;                  // max X region (DIL4: 45 segs)
    __shared__ __align__(1024) char lds[SCOO + 256];
    float* sco = (float*)(lds + SCOO);

    const int bid  = blockIdx.x;
    const int xcd  = bid & 7;
    const int j    = bid >> 3;                   // 0..191
    const int b    = 2 * xcd + (j >= 96 ? 1 : 0);
    const int u    = j % 96;
    const int band = u / 24;                     // 0..3 (32-row band)
    const int v    = u % 24;
    const int br   = v % 3;
    const int t2   = v / 3;                      // 0..7
    const int wt   = t2 & 1;
    const int hb   = band * 4 + (t2 >> 1);       // hb in {4band..4band+3} for ALL dilations

    if (br == 0)
        conv_core2<1, 64>(b, hb, wt, xT, XH, XW, XPAD, aggF1, catT, 0,   poolc, lds, sco);
    else if (br == 1)
        conv_core2<2, 64>(b, hb, wt, xT, XH, XW, XPAD, aggF2, catT, 64,  poolc, lds, sco);
    else
        conv_core2<4, 64>(b, hb, wt, xT, XH, XW, XPAD, aggF3, catT, 128, poolc, lds, sco);
}

// ---------------- final conv + residual: 2 rows per wave (halved bytes/MFMA) ----------------
#define FF_ROWB 4224                 // 66 slots * 64 B
#define FF_XBY  42240                // 10 rows
#define FF_XSEG 42

__global__ __launch_bounds__(256, 2)
void conv_final(const bf16* __restrict__ catT, const bf16* __restrict__ aggFt,
                const float* __restrict__ x, float* __restrict__ out)
{
    __shared__ __align__(1024) char lds[FF_XSEG * 1024];

    const int bid = blockIdx.x;                  // 512 blocks, XCD-banded
    const int xcd = bid & 7;
    const int j   = bid >> 3;                    // 0..63
    const int b   = 2 * xcd + (j >= 32 ? 1 : 0);
    const int u   = j & 31;
    const int wt  = u & 1;
    const int hb  = u >> 1;                      // 0..15 (8-row groups)

    const int tid  = threadIdx.x;
    const int wv   = tid >> 6;                   // 0..3, wave owns rows {2wv, 2wv+1}
    const int lane = tid & 63;
    const int n16  = lane & 15;
    const int g    = lane >> 4;

    const char* inB = (const char*)catT;
    const char* awB = (const char*)aggFt + (size_t)b * (6 * 36864);

    int baddr[12];
    #pragma unroll
    for (int nt = 0; nt < 4; ++nt)
        #pragma unroll
        for (int kw = 0; kw < 3; ++kw)
            baddr[nt*3+kw] = (2 * wv) * FF_ROWB + g * (66 * 16) + (nt * 16 + n16 + kw) * 16;

    int xoff[11];
    #pragma unroll
    for (int t = 0; t < 11; ++t) {
        int i = wv + 4 * t;
        xoff[t] = 0;
        if (i < FF_XSEG) {
            int o = i * 1024 + lane * 16;
            if (o < FF_XBY) {
                int row  = o / FF_ROWB;
                int rem  = o - row * FF_ROWB;
                int g2   = rem / (66 * 16);
                int slot = (rem - g2 * (66 * 16)) >> 4;
                int h_in = hb * 8 + row - 1;
                xoff[t] = ((b * CHH + CPAD + h_in) * CWD + (CPAD + wt * 64 - 1 + slot)) * (CATC * 2)
                          + g2 * 16;
            }
        }
    }

    auto stage = [&](int c) {
        #pragma unroll
        for (int t = 0; t < 11; ++t) {
            int i = wv + 4 * t;
            if (i >= FF_XSEG) break;
            __builtin_amdgcn_global_load_lds(
                (const __attribute__((address_space(1))) void*)(inB + (size_t)(xoff[t] + c * 64)),
                (__attribute__((address_space(3))) void*)(lds + i * 1024), 16, 0, 0);
        }
    };

    f32x4 acc[2][4][4];
    #pragma unroll
    for (int orr = 0; orr < 2; ++orr)
        #pragma unroll
        for (int nt = 0; nt < 4; ++nt)
            #pragma unroll
            for (int m = 0; m < 4; ++m) { f32x4 z = {0.f,0.f,0.f,0.f}; acc[orr][nt][m] = z; }

    for (int c = 0; c < 6; ++c) {
        stage(c);
        __syncthreads();
        const char* awC = awB + (size_t)c * 36864 + (size_t)lane * 16;
        __builtin_amdgcn_s_setprio(1);
        #pragma unroll
        for (int kw = 0; kw < 3; ++kw) {
            bf16x8 a[3][4];
            #pragma unroll
            for (int kh = 0; kh < 3; ++kh)
                #pragma unroll
                for (int m = 0; m < 4; ++m)
                    a[kh][m] = *(const bf16x8*)(awC + (size_t)(((kh * 3 + kw) * 4 + m) * 1024));
            #pragma unroll
            for (int nt = 0; nt < 4; ++nt) {
                bf16x8 bfr[4];
                #pragma unroll
                for (int rr = 0; rr < 4; ++rr)
                    bfr[rr] = *(const bf16x8*)(lds + baddr[nt * 3 + kw] + rr * FF_ROWB);
                #pragma unroll
                for (int kh = 0; kh < 3; ++kh)
                    #pragma unroll
                    for (int orr = 0; orr < 2; ++orr)
                        #pragma unroll
                        for (int m = 0; m < 4; ++m)
                            acc[orr][nt][m] = __builtin_amdgcn_mfma_f32_16x16x32_bf16(
                                a[kh][m], bfr[orr + kh], acc[orr][nt][m], 0, 0, 0);
            }
        }
        __builtin_amdgcn_s_setprio(0);
        __syncthreads();
    }

    #pragma unroll
    for (int orr = 0; orr < 2; ++orr) {
        const int h_out = hb * 8 + 2 * wv + orr;
        #pragma unroll
        for (int nt = 0; nt < 4; ++nt) {
            int w_out = wt * 64 + nt * 16 + n16;
            #pragma unroll
            for (int m = 0; m < 4; ++m) {
                int co = m * 16 + g * 4;
                size_t base = (((size_t)b * 64 + co) * HH + h_out) * WW + w_out;
                #pragma unroll
                for (int qq = 0; qq < 4; ++qq) {
                    size_t idx = base + (size_t)qq * HWSZ;
                    out[idx] = x[idx] + acc[orr][nt][m][qq];
                }
            }
        }
    }
}

// ---------------- launch ----------------
extern "C" void kernel_launch(void* const* d_in, const int* in_sizes, int n_in,
                              void* d_out, int out_size, void* d_ws, size_t ws_size,
                              hipStream_t stream) {
    const float* x      = (const float*)d_in[0];
    const float* w1     = (const float*)d_in[1];
    const float* fc1_1  = (const float*)d_in[2];
    const float* fc2w_1 = (const float*)d_in[3];
    const float* fc2b_1 = (const float*)d_in[4];
    const float* w2     = (const float*)d_in[5];
    const float* fc1_2  = (const float*)d_in[6];
    const float* fc2w_2 = (const float*)d_in[7];
    const float* fc2b_2 = (const float*)d_in[8];
    const float* w3     = (const float*)d_in[9];
    const float* fc1_3  = (const float*)d_in[10];
    const float* fc2w_3 = (const float*)d_in[11];
    const float* fc2b_3 = (const float*)d_in[12];
    const float* wt     = (const float*)d_in[13];
    const float* fc1_t  = (const float*)d_in[14];
    const float* fc2w_t = (const float*)d_in[15];
    const float* fc2b_t = (const float*)d_in[16];
    float* out = (float*)d_out;
    (void)in_sizes; (void)n_in; (void)out_size; (void)ws_size;

    char* ws = (char*)d_ws;
    auto alloc = [&](size_t bytes) { char* p = ws; ws += (bytes + 255) & ~(size_t)255; return p; };

    bf16*  aggF1   = (bf16*)alloc((size_t)BB * 18 * 4096);
    bf16*  aggF2   = (bf16*)alloc((size_t)BB * 18 * 4096);
    bf16*  aggF3   = (bf16*)alloc((size_t)BB * 18 * 4096);
    bf16*  aggFt   = (bf16*)alloc((size_t)BB * 54 * 4096);
    float* pooledx = (float*)alloc(BB * 64 * 4);
    float* pooledc = (float*)alloc(BB * 192 * 4);
    float* att1    = (float*)alloc(BB * 4 * 4);
    float* att2    = (float*)alloc(BB * 4 * 4);
    float* att3    = (float*)alloc(BB * 4 * 4);
    float* attt    = (float*)alloc(BB * 4 * 4);
    alloc(65536);                                            // guard
    const size_t XT_BYTES  = (size_t)BB * XH * XW * 64 * 2;
    bf16* xT   = (bf16*)alloc(XT_BYTES);
    alloc(65536);                                            // guard
    const size_t CAT_BYTES = (size_t)BB * CHH * CWD * CATC * 2;
    bf16* catT = (bf16*)alloc(CAT_BYTES);
    alloc(65536);                                            // guard

    // border + pooled zeroing, one launch
    init_borders<<<dim3(1056, 2), 256, 0, stream>>>(xT, catT, pooledx, pooledc);

    transpose_pad_pool_x<<<dim3(128, 16), 256, 0, stream>>>(x, xT, pooledx);

    attention3<<<dim3(16, 3), 64, 0, stream>>>(pooledx,
        fc1_1, fc2w_1, fc2b_1, att1,
        fc1_2, fc2w_2, fc2b_2, att2,
        fc1_3, fc2w_3, fc2b_3, att3);

    aggw_frag3<<<dim3(64, 16, 3), 256, 0, stream>>>(w1, att1, aggF1,
                                                    w2, att2, aggF2,
                                                    w3, att3, aggF3);

    conv_branch3<<<1536, 256, 0, stream>>>(xT, aggF1, aggF2, aggF3, catT, pooledc);

    attention_one<<<16, 64, 0, stream>>>(pooledc, CATC, fc1_t, 49, fc2w_t, fc2b_t, attt);
    aggw_frag_t<<<dim3(64, 16), 256, 0, stream>>>(wt, attt, aggFt);

    conv_final<<<512, 256, 0, stream>>>(catT, aggFt, x, out);
}